// Round 2
// baseline (3059.596 us; speedup 1.0000x reference)
//
#include <hip/hip_runtime.h>

#define IN_C  256
#define HID_C 128
#define OUT_C 2
#define BSH   7                    // nodes per bucket = 128
#define NB    128
#define CSH   14                   // src chunk = 16384 rows (2MB half-row window)
#define ACC_S 65                   // LDS acc stride (odd -> spread banks)

typedef __attribute__((ext_vector_type(8))) short short8;
typedef __attribute__((ext_vector_type(4))) float float4v;

__device__ __forceinline__ unsigned short f2bf(float f) {   // RNE float->bf16
    unsigned u = __float_as_uint(f);
    unsigned r = 0x7fffu + ((u >> 16) & 1u);
    return (unsigned short)((u + r) >> 16);
}
__device__ __forceinline__ unsigned pk2(float a, float b) {
    return (unsigned)f2bf(a) | ((unsigned)f2bf(b) << 16);
}
__device__ __forceinline__ float bl(unsigned u) { return __uint_as_float(u << 16); }
__device__ __forceinline__ float bh(unsigned u) { return __uint_as_float(u & 0xffff0000u); }

// ---- W1^T bf16 precompute --------------------------------------------------
__global__ void k_wT(const float* __restrict__ W1, unsigned short* __restrict__ w1t) {
    int i = blockIdx.x * 256 + threadIdx.x;     // i = c*256 + k (write-coalesced)
    if (i >= HID_C * IN_C) return;
    int c = i >> 8, k = i & 255;
    w1t[i] = f2bf(W1[(size_t)k * HID_C + c]);
}

// ---- pass 1a: per-wg (bucket,chunk) histogram -> gcnt[key*W + w] -----------
__global__ __launch_bounds__(256) void k_count(const int* __restrict__ ei,
                                               int* __restrict__ gcnt,
                                               int E, int K2, int NCH, int W, int CHv) {
    extern __shared__ int lh[];                // K2 ints
    int w = blockIdx.x, t = threadIdx.x;
    for (int b = t; b < K2; b += 256) lh[b] = 0;
    __syncthreads();
    int j0 = w * CHv;
    int j1 = min(j0 + CHv, E);
    for (int j = j0 + t; j < j1; j += 256) {
        int s = ei[j], d = ei[E + j];
        atomicAdd(&lh[(d >> BSH) * NCH + (s >> CSH)], 1);
    }
    __syncthreads();
    for (int b = t; b < K2; b += 256) gcnt[(size_t)b * W + w] = lh[b];
}

// ---- scan: 4096 elems/block ------------------------------------------------
__global__ __launch_bounds__(256) void k_scanA4(const int* __restrict__ cnt,
                                                int* __restrict__ excl,
                                                int* __restrict__ bsum, int n) {
    __shared__ int ss[256];
    int t = threadIdx.x;
    int base = blockIdx.x * 4096 + t * 16;
    int v[16]; int s = 0;
#pragma unroll
    for (int q = 0; q < 16; q++) { v[q] = (base + q < n) ? cnt[base + q] : 0; s += v[q]; }
    ss[t] = s;
    __syncthreads();
    for (int d = 1; d < 256; d <<= 1) {
        int x = (t >= d) ? ss[t - d] : 0;
        __syncthreads();
        ss[t] += x;
        __syncthreads();
    }
    int pre = (t == 0) ? 0 : ss[t - 1];
    if (t == 255) bsum[blockIdx.x] = ss[255];
    int run = pre;
#pragma unroll
    for (int q = 0; q < 16; q++) { if (base + q < n) excl[base + q] = run; run += v[q]; }
}

// scan of up to 1024 block sums, 4 per thread, in place -> exclusive
__global__ __launch_bounds__(256) void k_scanB(int* __restrict__ bsum, int nb) {
    __shared__ int ss[256];
    int t = threadIdx.x;
    int v[4]; int s = 0;
#pragma unroll
    for (int q = 0; q < 4; q++) {
        int idx = t * 4 + q;
        v[q] = (idx < nb) ? bsum[idx] : 0; s += v[q];
    }
    ss[t] = s;
    __syncthreads();
    for (int d = 1; d < 256; d <<= 1) {
        int x = (t >= d) ? ss[t - d] : 0;
        __syncthreads();
        ss[t] += x;
        __syncthreads();
    }
    int run = (t == 0) ? 0 : ss[t - 1];
#pragma unroll
    for (int q = 0; q < 4; q++) {
        int idx = t * 4 + q;
        if (idx < nb) bsum[idx] = run;
        run += v[q];
    }
}

__global__ void k_scanC4(int* __restrict__ gpos, const int* __restrict__ bsum, int n) {
    int i = blockIdx.x * 256 + threadIdx.x;
    if (i < n) gpos[i] += bsum[i >> 12];
}

// ---- pass 1c: place edges into ebuf, (bucket,chunk)-grouped ----------------
// ebuf entry: {src | dstloc<<17, w_f32}   (src < 2^17, dstloc < 128)
__global__ __launch_bounds__(256) void k_place(const int* __restrict__ ei,
                                               const float* __restrict__ w,
                                               const int* __restrict__ gpos,
                                               int2* __restrict__ ebuf,
                                               int E, int K2, int NCH, int W, int CHv) {
    extern __shared__ int lc[];                // K2 cursors
    int wg = blockIdx.x, t = threadIdx.x;
    for (int b = t; b < K2; b += 256) lc[b] = gpos[(size_t)b * W + wg];
    __syncthreads();
    int j0 = wg * CHv;
    int j1 = min(j0 + CHv, E);
    for (int j = j0 + t; j < j1; j += 256) {
        int s = ei[j], d = ei[E + j];
        float wv = w[j];
        int key = (d >> BSH) * NCH + (s >> CSH);
        int pos = atomicAdd(&lc[key], 1);
        ebuf[pos] = make_int2(s | ((d & (NB - 1)) << 17), __float_as_int(wv));
    }
}

// ---- dinv: per-bucket weight sums via LDS f32 atomics ----------------------
__global__ __launch_bounds__(256) void k_dinv(const int* __restrict__ gq,
                                              const int2* __restrict__ ebuf,
                                              float* __restrict__ dinv,
                                              int W, int NCH, int E, int K, int N) {
    __shared__ float wsum[NB];
    int b = blockIdx.x, t = threadIdx.x;
    int base = gq[(size_t)(b * NCH) * W];
    int next = (b + 1 < K) ? gq[(size_t)((b + 1) * NCH) * W] : E;
    if (t < NB) wsum[t] = 1.0f;                // self-loop weight
    __syncthreads();
    for (int j = base + t; j < next; j += 256) {
        int2 r = ebuf[j];
        atomicAdd(&wsum[(r.x >> 17) & (NB - 1)], __int_as_float(r.y));
    }
    __syncthreads();
    if (t < NB) {
        int node = b * NB + t;
        if (node < N) dinv[node] = rsqrtf(wsum[t]);
    }
}

// ---- GEMM1 (MFMA bf16): h1b[N,128] = dinv[.] * (x[N,256] @ W1) -------------
#define XS_LD 36
#define WT_LD 260
__global__ __launch_bounds__(256) void k_gemm1(const float* __restrict__ x,
                                               const unsigned short* __restrict__ w1t,
                                               const float* __restrict__ dinv,
                                               unsigned short* __restrict__ h1b, int n) {
    __shared__ __align__(16) unsigned short wt[HID_C * WT_LD];
    __shared__ __align__(16) unsigned short xs[64 * XS_LD];
    int tid  = threadIdx.x;
    int row0 = blockIdx.x * 64;
    for (int it = 0; it < 16; it++) {
        int idx = it * 256 + tid;
        int c = idx >> 5, kc = idx & 31;
        uint4 v = *(const uint4*)(w1t + (size_t)c * IN_C + kc * 8);
        uint2* dst = (uint2*)(wt + c * WT_LD + kc * 8);
        dst[0] = make_uint2(v.x, v.y);
        dst[1] = make_uint2(v.z, v.w);
    }
    int wv = tid >> 6, ln = tid & 63;
    int m = ln & 15, quad = ln >> 4;
    float4v acc[8];
#pragma unroll
    for (int ct = 0; ct < 8; ct++) acc[ct] = (float4v){0.f, 0.f, 0.f, 0.f};

    for (int k0 = 0; k0 < IN_C; k0 += 32) {
        __syncthreads();
        {
            int r = tid >> 2, s4 = tid & 3;
            int gr = row0 + r; if (gr >= n) gr = n - 1;
            const float4* px = (const float4*)(x + (size_t)gr * IN_C + k0 + s4 * 8);
            float4 a = px[0], bq = px[1];
            uint2* d = (uint2*)(xs + r * XS_LD + s4 * 8);
            d[0] = make_uint2(pk2(a.x, a.y), pk2(a.z, a.w));
            d[1] = make_uint2(pk2(bq.x, bq.y), pk2(bq.z, bq.w));
        }
        __syncthreads();
        union { uint2 u[2]; short8 v; } af;
        const uint2* pa = (const uint2*)(xs + (wv * 16 + m) * XS_LD + quad * 8);
        af.u[0] = pa[0]; af.u[1] = pa[1];
#pragma unroll
        for (int ct = 0; ct < 8; ct++) {
            union { uint2 u[2]; short8 v; } bf;
            const uint2* pb = (const uint2*)(wt + (ct * 16 + m) * WT_LD + k0 + quad * 8);
            bf.u[0] = pb[0]; bf.u[1] = pb[1];
            acc[ct] = __builtin_amdgcn_mfma_f32_16x16x32_bf16(af.v, bf.v, acc[ct], 0, 0, 0);
        }
    }
    __syncthreads();
    // fold dinv[row] into the stored features: h1b' = dinv * (x@W1)
    float4 dv = *(const float4*)(dinv + row0 + wv * 16 + quad * 4);
    const float* dvf = (const float*)&dv;
    unsigned short* ot = wt;
#pragma unroll
    for (int ct = 0; ct < 8; ct++)
#pragma unroll
        for (int r = 0; r < 4; r++)
            ot[(wv * 16 + quad * 4 + r) * 136 + ct * 16 + m] = f2bf(acc[ct][r] * dvf[r]);
    __syncthreads();
#pragma unroll
    for (int p = 0; p < 4; p++) {
        int idx = p * 256 + tid;
        int r = idx >> 4, c8 = idx & 15;
        if (row0 + r < n)
            *(uint4*)(h1b + (size_t)(row0 + r) * HID_C + c8 * 8) =
                *(const uint4*)(ot + r * 136 + c8 * 8);
    }
}

// ---- layer-1 aggregation + fused gemm2 (LDS acc, chunk-ordered edges) ------
// Block per bucket (all 782 co-resident). ebuf is (bucket, src-chunk)-sorted,
// so all blocks gather from the same ~2MB h1b window at any instant -> L2 hits.
// Two 64-channel sweeps keep LDS at 33KB (4 blocks/CU).
__global__ __launch_bounds__(256) void k_agg1(const int* __restrict__ gq,
                                              const int2* __restrict__ ebuf,
                                              const unsigned short* __restrict__ h1b,
                                              const float* __restrict__ dinv,
                                              const float* __restrict__ b1,
                                              const float* __restrict__ W2,
                                              float* __restrict__ h2,
                                              int W, int NCH, int E, int K, int N) {
    __shared__ float acc[NB * ACC_S];
    __shared__ float pd[NB][2];
    int b = blockIdx.x, t = threadIdx.x;
    int base = gq[(size_t)(b * NCH) * W];
    int next = (b + 1 < K) ? gq[(size_t)((b + 1) * NCH) * W] : E;
    int wave = t >> 6, lane = t & 63;
    int o = lane >> 3, c = lane & 7;       // octet = edge slot, c = 16B chunk
    if (t < NB) { pd[t][0] = 0.f; pd[t][1] = 0.f; }
    for (int h = 0; h < 2; h++) {
        int hoff = h << 6;                 // channel offset (64 per sweep)
        for (int i = t; i < NB * ACC_S; i += 256) acc[i] = 0.f;
        __syncthreads();
        for (int j = base + (wave << 4); j < next; j += 64) {
            int e0 = j + o, e1 = j + 8 + o;
            int2 r0 = ebuf[min(e0, next - 1)];
            int2 r1 = ebuf[min(e1, next - 1)];
            float w0 = (e0 < next) ? __int_as_float(r0.y) : 0.f;
            float w1 = (e1 < next) ? __int_as_float(r1.y) : 0.f;
            int s0 = r0.x & 0x1FFFF, s1 = r1.x & 0x1FFFF;
            int d0 = (r0.x >> 17) & (NB - 1), d1 = (r1.x >> 17) & (NB - 1);
            uint4 p0 = *(const uint4*)(h1b + ((size_t)s0 << 7) + hoff + (c << 3));
            uint4 p1 = *(const uint4*)(h1b + ((size_t)s1 << 7) + hoff + (c << 3));
            float* a0 = acc + d0 * ACC_S + (c << 3);
            float* a1 = acc + d1 * ACC_S + (c << 3);
            atomicAdd(a0 + 0, w0 * bl(p0.x)); atomicAdd(a0 + 1, w0 * bh(p0.x));
            atomicAdd(a0 + 2, w0 * bl(p0.y)); atomicAdd(a0 + 3, w0 * bh(p0.y));
            atomicAdd(a0 + 4, w0 * bl(p0.z)); atomicAdd(a0 + 5, w0 * bh(p0.z));
            atomicAdd(a0 + 6, w0 * bl(p0.w)); atomicAdd(a0 + 7, w0 * bh(p0.w));
            atomicAdd(a1 + 0, w1 * bl(p1.x)); atomicAdd(a1 + 1, w1 * bh(p1.x));
            atomicAdd(a1 + 2, w1 * bl(p1.y)); atomicAdd(a1 + 3, w1 * bh(p1.y));
            atomicAdd(a1 + 4, w1 * bl(p1.z)); atomicAdd(a1 + 5, w1 * bh(p1.z));
            atomicAdd(a1 + 6, w1 * bl(p1.w)); atomicAdd(a1 + 7, w1 * bh(p1.w));
        }
        __syncthreads();
        // epilogue for this half: +self, *dinv, +b1, relu, partial W2 dot
        {
            int nd = t >> 1, sub = t & 1;
            int node = b * NB + nd;
            float s0 = 0.f, s1 = 0.f;
            if (node < N) {
                float di = dinv[node];
                const unsigned short* selfp = h1b + ((size_t)node << 7) + hoff + sub * 32;
                const float* accp = acc + nd * ACC_S + sub * 32;
#pragma unroll
                for (int cc = 0; cc < 32; cc++) {
                    int gch = hoff + sub * 32 + cc;
                    float sv = __uint_as_float((unsigned)selfp[cc] << 16);
                    float hv = fmaf(di, accp[cc] + sv, b1[gch]);
                    hv = fmaxf(hv, 0.f);
                    s0 = fmaf(hv, W2[gch * 2 + 0], s0);
                    s1 = fmaf(hv, W2[gch * 2 + 1], s1);
                }
            }
            s0 += __shfl_xor(s0, 1);
            s1 += __shfl_xor(s1, 1);
            if (sub == 0 && node < N) { pd[nd][0] += s0; pd[nd][1] += s1; }
        }
        __syncthreads();
    }
    if (t < NB) {
        int node = b * NB + t;
        if (node < N) {
            float di = dinv[node];
            ((float2*)h2)[node] = make_float2(di * pd[t][0], di * pd[t][1]);
        }
    }
}

// ---- layer-2 aggregation: block per bucket, LDS acc (h2 is L2-resident) ----
__global__ __launch_bounds__(256) void k_agg2(const int* __restrict__ gq,
                                              const int2* __restrict__ ebuf,
                                              const float* __restrict__ h2,
                                              const float* __restrict__ dinv,
                                              const float* __restrict__ b2,
                                              float* __restrict__ out,
                                              int W, int NCH, int E, int K, int N) {
    __shared__ float a2[NB * 2];
    int b = blockIdx.x, t = threadIdx.x;
    int base = gq[(size_t)(b * NCH) * W];
    int next = (b + 1 < K) ? gq[(size_t)((b + 1) * NCH) * W] : E;
    if (t < NB * 2) a2[t] = 0.f;
    __syncthreads();
    for (int j = base + t; j < next; j += 256) {
        int2 r = ebuf[j];
        float w = __int_as_float(r.y);
        int s = r.x & 0x1FFFF, dl = (r.x >> 17) & (NB - 1);
        float2 v = ((const float2*)h2)[s];
        atomicAdd(&a2[dl * 2 + 0], w * v.x);
        atomicAdd(&a2[dl * 2 + 1], w * v.y);
    }
    __syncthreads();
    if (t < NB) {
        int node = b * NB + t;
        if (node < N) {
            float di = dinv[node];
            float2 hv = ((const float2*)h2)[node];   // already dinv*H2
            ((float2*)out)[node] = make_float2(b2[0] + di * (a2[t * 2 + 0] + hv.x),
                                               b2[1] + di * (a2[t * 2 + 1] + hv.y));
        }
    }
}

extern "C" void kernel_launch(void* const* d_in, const int* in_sizes, int n_in,
                              void* d_out, int out_size, void* d_ws, size_t ws_size,
                              hipStream_t stream) {
    const float* x  = (const float*)d_in[0];
    const int*   ei = (const int*)d_in[1];   // [2,E] int32
    const float* ew = (const float*)d_in[2];
    const float* W1 = (const float*)d_in[3];
    const float* b1 = (const float*)d_in[4];
    const float* W2 = (const float*)d_in[5];
    const float* b2 = (const float*)d_in[6];
    float* out = (float*)d_out;

    int N = in_sizes[0] / IN_C;
    int E = in_sizes[2];
    int K = (N + NB - 1) >> BSH;             // buckets (782)
    int NCH = (N + (1 << CSH) - 1) >> CSH;   // src chunks (7)
    int K2 = K * NCH;                        // sort keys (5474)
    int W = 256;                             // pass-1 workgroups = CU count
    int CHv = (E + W - 1) / W;               // edges per workgroup
    int KW2 = K2 * W;

    char* ws = (char*)d_ws;
    float* dinv   = (float*)ws; ws += (size_t)N * 4;
    int*   gcnt   = (int*)ws;   ws += (size_t)KW2 * 4;
    int*   bsum   = (int*)ws;   ws += 4096;
    int2*  ebuf   = (int2*)ws;  ws += (size_t)E * 8;
    unsigned short* w1t = (unsigned short*)ws; ws += (size_t)HID_C * IN_C * 2;
    unsigned short* h1b = (unsigned short*)ws; ws += (size_t)N * HID_C * 2;
    float* h2     = (float*)ws; ws += (size_t)N * OUT_C * 4;

    int nb_s4 = (KW2 + 4095) / 4096;         // 343 (<=1024 for k_scanB)
    int nb_sc = (KW2 + 255) / 256;
    size_t lds_k2 = (size_t)K2 * 4;          // ~21.9 KB dynamic LDS

    k_wT    <<<(HID_C * IN_C + 255) / 256, 256, 0, stream>>>(W1, w1t);
    k_count <<<W, 256, lds_k2, stream>>>(ei, gcnt, E, K2, NCH, W, CHv);
    k_scanA4<<<nb_s4, 256, 0, stream>>>(gcnt, gcnt, bsum, KW2);
    k_scanB <<<1, 256, 0, stream>>>(bsum, nb_s4);
    k_scanC4<<<nb_sc, 256, 0, stream>>>(gcnt, bsum, KW2);
    k_place <<<W, 256, lds_k2, stream>>>(ei, ew, gcnt, ebuf, E, K2, NCH, W, CHv);
    k_dinv  <<<K, 256, 0, stream>>>(gcnt, ebuf, dinv, W, NCH, E, K, N);
    k_gemm1 <<<(N + 63) / 64, 256, 0, stream>>>(x, w1t, dinv, h1b, N);
    k_agg1  <<<K, 256, 0, stream>>>(gcnt, ebuf, h1b, dinv, b1, W2, h2, W, NCH, E, K, N);
    k_agg2  <<<K, 256, 0, stream>>>(gcnt, ebuf, h2, dinv, b2, out, W, NCH, E, K, N);
}

// Round 3
// 674.157 us; speedup vs baseline: 4.5384x; 4.5384x over previous
//
#include <hip/hip_runtime.h>

#define IN_C  256
#define HID_C 128
#define OUT_C 2
#define BSH   7                    // nodes per bucket = 128
#define NB    128
#define CSH   13                   // src chunk = 8192 rows (2MB full-row window)
#define SEGCAP 640                 // per-(bucket,chunk) LDS segment capacity

typedef __attribute__((ext_vector_type(8))) short short8;
typedef __attribute__((ext_vector_type(4))) float float4v;

__device__ __forceinline__ unsigned short f2bf(float f) {   // RNE float->bf16
    unsigned u = __float_as_uint(f);
    unsigned r = 0x7fffu + ((u >> 16) & 1u);
    return (unsigned short)((u + r) >> 16);
}
__device__ __forceinline__ unsigned pk2(float a, float b) {
    return (unsigned)f2bf(a) | ((unsigned)f2bf(b) << 16);
}
__device__ __forceinline__ float bl(unsigned u) { return __uint_as_float(u << 16); }
__device__ __forceinline__ float bh(unsigned u) { return __uint_as_float(u & 0xffff0000u); }

// ---- W1^T bf16 precompute --------------------------------------------------
__global__ void k_wT(const float* __restrict__ W1, unsigned short* __restrict__ w1t) {
    int i = blockIdx.x * 256 + threadIdx.x;     // i = c*256 + k (write-coalesced)
    if (i >= HID_C * IN_C) return;
    int c = i >> 8, k = i & 255;
    w1t[i] = f2bf(W1[(size_t)k * HID_C + c]);
}

// ---- pass 1a: per-wg (bucket,chunk) histogram -> gcnt[key*W + w] -----------
__global__ __launch_bounds__(256) void k_count(const int* __restrict__ ei,
                                               int* __restrict__ gcnt,
                                               int E, int K2, int NCH, int W, int CHv) {
    extern __shared__ int lh[];                // K2 ints
    int w = blockIdx.x, t = threadIdx.x;
    for (int b = t; b < K2; b += 256) lh[b] = 0;
    __syncthreads();
    int j0 = w * CHv;
    int j1 = min(j0 + CHv, E);
    for (int j = j0 + t; j < j1; j += 256) {
        int s = ei[j], d = ei[E + j];
        atomicAdd(&lh[(d >> BSH) * NCH + (s >> CSH)], 1);
    }
    __syncthreads();
    for (int b = t; b < K2; b += 256) gcnt[(size_t)b * W + w] = lh[b];
}

// ---- scan: 4096 elems/block ------------------------------------------------
__global__ __launch_bounds__(256) void k_scanA4(const int* __restrict__ cnt,
                                                int* __restrict__ excl,
                                                int* __restrict__ bsum, int n) {
    __shared__ int ss[256];
    int t = threadIdx.x;
    int base = blockIdx.x * 4096 + t * 16;
    int v[16]; int s = 0;
#pragma unroll
    for (int q = 0; q < 16; q++) { v[q] = (base + q < n) ? cnt[base + q] : 0; s += v[q]; }
    ss[t] = s;
    __syncthreads();
    for (int d = 1; d < 256; d <<= 1) {
        int x = (t >= d) ? ss[t - d] : 0;
        __syncthreads();
        ss[t] += x;
        __syncthreads();
    }
    int pre = (t == 0) ? 0 : ss[t - 1];
    if (t == 255) bsum[blockIdx.x] = ss[255];
    int run = pre;
#pragma unroll
    for (int q = 0; q < 16; q++) { if (base + q < n) excl[base + q] = run; run += v[q]; }
}

// scan of up to 2048 block sums, 8 per thread, in place -> exclusive
__global__ __launch_bounds__(256) void k_scanB(int* __restrict__ bsum, int nb) {
    __shared__ int ss[256];
    int t = threadIdx.x;
    int v[8]; int s = 0;
#pragma unroll
    for (int q = 0; q < 8; q++) {
        int idx = t * 8 + q;
        v[q] = (idx < nb) ? bsum[idx] : 0; s += v[q];
    }
    ss[t] = s;
    __syncthreads();
    for (int d = 1; d < 256; d <<= 1) {
        int x = (t >= d) ? ss[t - d] : 0;
        __syncthreads();
        ss[t] += x;
        __syncthreads();
    }
    int run = (t == 0) ? 0 : ss[t - 1];
#pragma unroll
    for (int q = 0; q < 8; q++) {
        int idx = t * 8 + q;
        if (idx < nb) bsum[idx] = run;
        run += v[q];
    }
}

__global__ void k_scanC4(int* __restrict__ gpos, const int* __restrict__ bsum, int n) {
    int i = blockIdx.x * 256 + threadIdx.x;
    if (i < n) gpos[i] += bsum[i >> 12];
}

// ---- pass 1c: place edges into ebuf, (bucket,chunk)-grouped ----------------
// ebuf entry: {src | dstloc<<17, w_f32}   (src < 2^17, dstloc < 128)
__global__ __launch_bounds__(256) void k_place(const int* __restrict__ ei,
                                               const float* __restrict__ w,
                                               const int* __restrict__ gpos,
                                               int2* __restrict__ ebuf,
                                               int E, int K2, int NCH, int W, int CHv) {
    extern __shared__ int lc[];                // K2 cursors
    int wg = blockIdx.x, t = threadIdx.x;
    for (int b = t; b < K2; b += 256) lc[b] = gpos[(size_t)b * W + wg];
    __syncthreads();
    int j0 = wg * CHv;
    int j1 = min(j0 + CHv, E);
    for (int j = j0 + t; j < j1; j += 256) {
        int s = ei[j], d = ei[E + j];
        float wv = w[j];
        int key = (d >> BSH) * NCH + (s >> CSH);
        int pos = atomicAdd(&lc[key], 1);
        ebuf[pos] = make_int2(s | ((d & (NB - 1)) << 17), __float_as_int(wv));
    }
}

// ---- dinv: per-bucket weight sums via LDS f32 atomics ----------------------
__global__ __launch_bounds__(256) void k_dinv(const int* __restrict__ gq,
                                              const int2* __restrict__ ebuf,
                                              float* __restrict__ dinv,
                                              int W, int NCH, int E, int K, int N) {
    __shared__ float wsum[NB];
    int b = blockIdx.x, t = threadIdx.x;
    int base = gq[(size_t)(b * NCH) * W];
    int next = (b + 1 < K) ? gq[(size_t)((b + 1) * NCH) * W] : E;
    if (t < NB) wsum[t] = 1.0f;                // self-loop weight
    __syncthreads();
    for (int j = base + t; j < next; j += 256) {
        int2 r = ebuf[j];
        atomicAdd(&wsum[(r.x >> 17) & (NB - 1)], __int_as_float(r.y));
    }
    __syncthreads();
    if (t < NB) {
        int node = b * NB + t;
        if (node < N) dinv[node] = rsqrtf(wsum[t]);
    }
}

// ---- GEMM1 (MFMA bf16): h1b[N,128] = dinv[.] * (x[N,256] @ W1) -------------
#define XS_LD 36
#define WT_LD 260
__global__ __launch_bounds__(256) void k_gemm1(const float* __restrict__ x,
                                               const unsigned short* __restrict__ w1t,
                                               const float* __restrict__ dinv,
                                               unsigned short* __restrict__ h1b, int n) {
    __shared__ __align__(16) unsigned short wt[HID_C * WT_LD];
    __shared__ __align__(16) unsigned short xs[64 * XS_LD];
    int tid  = threadIdx.x;
    int row0 = blockIdx.x * 64;
    for (int it = 0; it < 16; it++) {
        int idx = it * 256 + tid;
        int c = idx >> 5, kc = idx & 31;
        uint4 v = *(const uint4*)(w1t + (size_t)c * IN_C + kc * 8);
        uint2* dst = (uint2*)(wt + c * WT_LD + kc * 8);
        dst[0] = make_uint2(v.x, v.y);
        dst[1] = make_uint2(v.z, v.w);
    }
    int wv = tid >> 6, ln = tid & 63;
    int m = ln & 15, quad = ln >> 4;
    float4v acc[8];
#pragma unroll
    for (int ct = 0; ct < 8; ct++) acc[ct] = (float4v){0.f, 0.f, 0.f, 0.f};

    for (int k0 = 0; k0 < IN_C; k0 += 32) {
        __syncthreads();
        {
            int r = tid >> 2, s4 = tid & 3;
            int gr = row0 + r; if (gr >= n) gr = n - 1;
            const float4* px = (const float4*)(x + (size_t)gr * IN_C + k0 + s4 * 8);
            float4 a = px[0], bq = px[1];
            uint2* d = (uint2*)(xs + r * XS_LD + s4 * 8);
            d[0] = make_uint2(pk2(a.x, a.y), pk2(a.z, a.w));
            d[1] = make_uint2(pk2(bq.x, bq.y), pk2(bq.z, bq.w));
        }
        __syncthreads();
        union { uint2 u[2]; short8 v; } af;
        const uint2* pa = (const uint2*)(xs + (wv * 16 + m) * XS_LD + quad * 8);
        af.u[0] = pa[0]; af.u[1] = pa[1];
#pragma unroll
        for (int ct = 0; ct < 8; ct++) {
            union { uint2 u[2]; short8 v; } bf;
            const uint2* pb = (const uint2*)(wt + (ct * 16 + m) * WT_LD + k0 + quad * 8);
            bf.u[0] = pb[0]; bf.u[1] = pb[1];
            acc[ct] = __builtin_amdgcn_mfma_f32_16x16x32_bf16(af.v, bf.v, acc[ct], 0, 0, 0);
        }
    }
    __syncthreads();
    // fold dinv[row] into the stored features: h1b' = dinv * (x@W1)
    float4 dv = *(const float4*)(dinv + row0 + wv * 16 + quad * 4);
    const float* dvf = (const float*)&dv;
    unsigned short* ot = wt;
#pragma unroll
    for (int ct = 0; ct < 8; ct++)
#pragma unroll
        for (int r = 0; r < 4; r++)
            ot[(wv * 16 + quad * 4 + r) * 136 + ct * 16 + m] = f2bf(acc[ct][r] * dvf[r]);
    __syncthreads();
#pragma unroll
    for (int p = 0; p < 4; p++) {
        int idx = p * 256 + tid;
        int r = idx >> 4, c8 = idx & 15;
        if (row0 + r < n)
            *(uint4*)(h1b + (size_t)(row0 + r) * HID_C + c8 * 8) =
                *(const uint4*)(ot + r * 136 + c8 * 8);
    }
}

// ---- layer-1 aggregation + fused gemm2 -------------------------------------
// Block per bucket (all ~782 co-resident), edges (bucket,chunk)-sorted.
// Per (bucket,chunk): dst-sort the ~315-edge segment in LDS (hist + wave
// prefix + scatter), then 4 waves x 32 dsts each: quad (16 lanes) processes
// one dst run with dwordx4 gathers, accumulating in registers (acc[8][8],
// statically indexed). No atomics on the hot path; gathers hit the 2MB
// chunk window in L2.
__global__ __launch_bounds__(256) void k_agg1(const int* __restrict__ gq,
                                              const int2* __restrict__ ebuf,
                                              const unsigned short* __restrict__ h1b,
                                              const float* __restrict__ dinv,
                                              const float* __restrict__ b1,
                                              const float* __restrict__ W2,
                                              float* __restrict__ h2,
                                              int W, int NCH, int E, int K, int N) {
    __shared__ int2 ls[SEGCAP];
    __shared__ int lh[NB], lex[NB], lc[NB];
    int b = blockIdx.x, t = threadIdx.x;
    int wv = t >> 6, lane = t & 63;
    int g = lane >> 4, c16 = lane & 15;    // quad id, 16B chunk within row
    float au[8][8];
#pragma unroll
    for (int u = 0; u < 8; u++)
#pragma unroll
        for (int k = 0; k < 8; k++) au[u][k] = 0.f;

    for (int ch = 0; ch < NCH; ch++) {
        int kb = gq[(size_t)(b * NCH + ch) * W];
        int ke = (b * NCH + ch + 1 < K * NCH) ? gq[(size_t)(b * NCH + ch + 1) * W] : E;
        for (int off = kb; off < ke; off += SEGCAP) {
            int m = min(SEGCAP, ke - off);
            __syncthreads();                       // previous ls/lh users done
            if (t < NB) lh[t] = 0;
            __syncthreads();
            for (int i = t; i < m; i += 256)
                atomicAdd(&lh[(ebuf[off + i].x >> 17) & (NB - 1)], 1);
            __syncthreads();
            if (t < 64) {                          // wave-0 prefix over 128
                int a = lh[2 * t], bb = lh[2 * t + 1];
                int s = a + bb;
                for (int d = 1; d < 64; d <<= 1) {
                    int v = __shfl_up(s, d);
                    if (t >= d) s += v;
                }
                int ep = s - (a + bb);             // exclusive at pair start
                lex[2 * t] = ep;     lc[2 * t] = ep;
                lex[2 * t + 1] = ep + a; lc[2 * t + 1] = ep + a;
            }
            __syncthreads();
            for (int i = t; i < m; i += 256) {     // scatter: dst-sorted list
                int2 e = ebuf[off + i];
                int pos = atomicAdd(&lc[(e.x >> 17) & (NB - 1)], 1);
                ls[pos] = e;
            }
            __syncthreads();
#pragma unroll
            for (int u = 0; u < 8; u++) {          // 4 quads x 8 = 32 dsts/wave
                int d = wv * 32 + u * 4 + g;
                int jb = lex[d], je = jb + lh[d];
                for (int j = jb; j < je; j++) {
                    int2 rec = ls[j];              // quad-uniform LDS read
                    float wgt = __int_as_float(rec.y);
                    int s = rec.x & 0x1FFFF;
                    uint4 p = *(const uint4*)(h1b + ((size_t)s << 7) + c16 * 8);
                    au[u][0] = fmaf(wgt, bl(p.x), au[u][0]);
                    au[u][1] = fmaf(wgt, bh(p.x), au[u][1]);
                    au[u][2] = fmaf(wgt, bl(p.y), au[u][2]);
                    au[u][3] = fmaf(wgt, bh(p.y), au[u][3]);
                    au[u][4] = fmaf(wgt, bl(p.z), au[u][4]);
                    au[u][5] = fmaf(wgt, bh(p.z), au[u][5]);
                    au[u][6] = fmaf(wgt, bl(p.w), au[u][6]);
                    au[u][7] = fmaf(wgt, bh(p.w), au[u][7]);
                }
            }
        }
    }
    // epilogue: +self, *dinv, +b1, relu, W2 dot, quad butterfly -> h2'
    float4 b1a = *(const float4*)(b1 + c16 * 8);
    float4 b1b = *(const float4*)(b1 + c16 * 8 + 4);
    const float* bap = (const float*)&b1a;
    const float* bbp = (const float*)&b1b;
    const float4* wp = (const float4*)(W2 + c16 * 16);   // rows c16*8..+7
    float4 w0 = wp[0], w1 = wp[1], w2 = wp[2], w3 = wp[3];
    const float* wf = (const float*)&w0;                 // 16 consecutive f32
#pragma unroll
    for (int u = 0; u < 8; u++) {
        int d = wv * 32 + u * 4 + g;
        int node = b * NB + d;
        bool valid = node < N;
        float di = valid ? dinv[node] : 0.f;
        uint4 sp; sp.x = sp.y = sp.z = sp.w = 0;
        if (valid) sp = *(const uint4*)(h1b + ((size_t)node << 7) + c16 * 8);
        float sf[8];
        sf[0] = bl(sp.x); sf[1] = bh(sp.x); sf[2] = bl(sp.y); sf[3] = bh(sp.y);
        sf[4] = bl(sp.z); sf[5] = bh(sp.z); sf[6] = bl(sp.w); sf[7] = bh(sp.w);
        float s0 = 0.f, s1 = 0.f;
        const float* wq[4] = { (const float*)&w0, (const float*)&w1,
                               (const float*)&w2, (const float*)&w3 };
#pragma unroll
        for (int k = 0; k < 8; k++) {
            float bk = (k < 4) ? bap[k] : bbp[k - 4];
            float hv = fmaf(di, au[u][k] + sf[k], bk);
            hv = fmaxf(hv, 0.f);
            s0 = fmaf(hv, wq[k >> 1][(k & 1) * 2 + 0], s0);
            s1 = fmaf(hv, wq[k >> 1][(k & 1) * 2 + 1], s1);
        }
#pragma unroll
        for (int dd = 1; dd < 16; dd <<= 1) {      // reduce across quad lanes
            s0 += __shfl_xor(s0, dd);
            s1 += __shfl_xor(s1, dd);
        }
        if (c16 == 0 && valid)
            ((float2*)h2)[node] = make_float2(di * s0, di * s1);
    }
}

// ---- layer-2 aggregation: block per bucket, per-wave private LDS acc -------
__global__ __launch_bounds__(256) void k_agg2(const int* __restrict__ gq,
                                              const int2* __restrict__ ebuf,
                                              const float* __restrict__ h2,
                                              const float* __restrict__ dinv,
                                              const float* __restrict__ b2,
                                              float* __restrict__ out,
                                              int W, int NCH, int E, int K, int N) {
    __shared__ float a2[4][NB * 2];
    int b = blockIdx.x, t = threadIdx.x;
    int wv = t >> 6;
    int base = gq[(size_t)(b * NCH) * W];
    int next = (b + 1 < K) ? gq[(size_t)((b + 1) * NCH) * W] : E;
    for (int i = t; i < 4 * NB * 2; i += 256) a2[i >> 8][i & 255] = 0.f;
    __syncthreads();
    for (int j = base + t; j < next; j += 256) {
        int2 r = ebuf[j];
        float w = __int_as_float(r.y);
        int s = r.x & 0x1FFFF, dl = (r.x >> 17) & (NB - 1);
        float2 v = ((const float2*)h2)[s];
        atomicAdd(&a2[wv][dl * 2 + 0], w * v.x);
        atomicAdd(&a2[wv][dl * 2 + 1], w * v.y);
    }
    __syncthreads();
    if (t < NB) {
        int node = b * NB + t;
        if (node < N) {
            float sx = a2[0][t * 2] + a2[1][t * 2] + a2[2][t * 2] + a2[3][t * 2];
            float sy = a2[0][t * 2 + 1] + a2[1][t * 2 + 1] + a2[2][t * 2 + 1] + a2[3][t * 2 + 1];
            float di = dinv[node];
            float2 hv = ((const float2*)h2)[node];   // already dinv*H2
            ((float2*)out)[node] = make_float2(b2[0] + di * (sx + hv.x),
                                               b2[1] + di * (sy + hv.y));
        }
    }
}

extern "C" void kernel_launch(void* const* d_in, const int* in_sizes, int n_in,
                              void* d_out, int out_size, void* d_ws, size_t ws_size,
                              hipStream_t stream) {
    const float* x  = (const float*)d_in[0];
    const int*   ei = (const int*)d_in[1];   // [2,E] int32
    const float* ew = (const float*)d_in[2];
    const float* W1 = (const float*)d_in[3];
    const float* b1 = (const float*)d_in[4];
    const float* W2 = (const float*)d_in[5];
    const float* b2 = (const float*)d_in[6];
    float* out = (float*)d_out;

    int N = in_sizes[0] / IN_C;
    int E = in_sizes[2];
    int K = (N + NB - 1) >> BSH;             // buckets (782)
    int NCH = (N + (1 << CSH) - 1) >> CSH;   // src chunks (13)
    int K2 = K * NCH;                        // sort keys (10166)
    int W = 512;                             // pass-1 workgroups (2/CU)
    int CHv = (E + W - 1) / W;               // edges per workgroup
    int KW2 = K2 * W;

    char* ws = (char*)d_ws;
    float* dinv   = (float*)ws; ws += (size_t)N * 4;
    int*   gcnt   = (int*)ws;   ws += (size_t)KW2 * 4;
    int*   bsum   = (int*)ws;   ws += 8192;
    int2*  ebuf   = (int2*)ws;  ws += (size_t)E * 8;
    unsigned short* w1t = (unsigned short*)ws; ws += (size_t)HID_C * IN_C * 2;
    unsigned short* h1b = (unsigned short*)ws; ws += (size_t)N * HID_C * 2;
    float* h2     = (float*)ws; ws += (size_t)N * OUT_C * 4;

    int nb_s4 = (KW2 + 4095) / 4096;         // ~1271 (<=2048 for k_scanB)
    int nb_sc = (KW2 + 255) / 256;
    size_t lds_k2 = (size_t)K2 * 4;          // ~40.7 KB dynamic LDS

    k_wT    <<<(HID_C * IN_C + 255) / 256, 256, 0, stream>>>(W1, w1t);
    k_count <<<W, 256, lds_k2, stream>>>(ei, gcnt, E, K2, NCH, W, CHv);
    k_scanA4<<<nb_s4, 256, 0, stream>>>(gcnt, gcnt, bsum, KW2);
    k_scanB <<<1, 256, 0, stream>>>(bsum, nb_s4);
    k_scanC4<<<nb_sc, 256, 0, stream>>>(gcnt, bsum, KW2);
    k_place <<<W, 256, lds_k2, stream>>>(ei, ew, gcnt, ebuf, E, K2, NCH, W, CHv);
    k_dinv  <<<K, 256, 0, stream>>>(gcnt, ebuf, dinv, W, NCH, E, K, N);
    k_gemm1 <<<(N + 63) / 64, 256, 0, stream>>>(x, w1t, dinv, h1b, N);
    k_agg1  <<<K, 256, 0, stream>>>(gcnt, ebuf, h1b, dinv, b1, W2, h2, W, NCH, E, K, N);
    k_agg2  <<<K, 256, 0, stream>>>(gcnt, ebuf, h2, dinv, b2, out, W, NCH, E, K, N);
}

// Round 4
// 550.451 us; speedup vs baseline: 5.5583x; 1.2247x over previous
//
#include <hip/hip_runtime.h>
#include <hip/hip_fp16.h>

#define IN_C  256
#define HID_C 128
#define OUT_C 2
#define BSH   7                    // nodes per bucket = 128
#define NB    128
#define CSH   13                   // src chunk = 8192 rows (2MB L2 window)
#define MAXNCH 16                  // max chunks (N < 131072)
#define NKMAX  (MAXNCH * NB)       // max fine keys per bucket (2048)
#define CAP    4608                // sortfine LDS staging capacity (mean 4092)

typedef __attribute__((ext_vector_type(8))) short short8;
typedef __attribute__((ext_vector_type(4))) float float4v;

__device__ __forceinline__ unsigned short f2bf(float f) {   // RNE float->bf16
    unsigned u = __float_as_uint(f);
    unsigned r = 0x7fffu + ((u >> 16) & 1u);
    return (unsigned short)((u + r) >> 16);
}
__device__ __forceinline__ unsigned pk2(float a, float b) {
    return (unsigned)f2bf(a) | ((unsigned)f2bf(b) << 16);
}
// packed edge: bits[16:0]=src (N<2^17), bits[31:17]=fp16(w) sans sign (w>=0)
__device__ __forceinline__ unsigned enc_edge(int src, float w) {
    unsigned h = (unsigned)(__half_as_ushort(__float2half(w)) & 0x7FFF);
    return (h << 17) | (unsigned)src;
}
__device__ __forceinline__ void dec_edge(unsigned rec, int& s, float& w) {
    s = (int)(rec & 0x1FFFFu);
    __half hh;
    *(unsigned short*)&hh = (unsigned short)(rec >> 17);
    w = __half2float(hh);
}
__device__ __forceinline__ float bl(unsigned u) { return __uint_as_float(u << 16); }
__device__ __forceinline__ float bh(unsigned u) { return __uint_as_float(u & 0xffff0000u); }

// ---- W1^T bf16 precompute --------------------------------------------------
__global__ void k_wT(const float* __restrict__ W1, unsigned short* __restrict__ w1t) {
    int i = blockIdx.x * 256 + threadIdx.x;
    if (i >= HID_C * IN_C) return;
    int c = i >> 8, k = i & 255;
    w1t[i] = f2bf(W1[(size_t)k * HID_C + c]);
}

// ---- pass 1a: per-wg bucket histogram -> gcnt[b*W + w] (782 keys, cheap) ---
__global__ __launch_bounds__(256) void k_count(const int* __restrict__ ei,
                                               int* __restrict__ gcnt,
                                               int E, int K, int W, int CHv) {
    extern __shared__ int lh[];                // K ints (~3.1 KB)
    int w = blockIdx.x, t = threadIdx.x;
    for (int b = t; b < K; b += 256) lh[b] = 0;
    __syncthreads();
    int j0 = w * CHv;
    int j1 = min(j0 + CHv, E);
    for (int j = j0 + t; j < j1; j += 256)
        atomicAdd(&lh[ei[E + j] >> BSH], 1);
    __syncthreads();
    for (int b = t; b < K; b += 256) gcnt[(size_t)b * W + w] = lh[b];
}

// ---- scan: 4096 elems/block ------------------------------------------------
__global__ __launch_bounds__(256) void k_scanA4(const int* __restrict__ cnt,
                                                int* __restrict__ excl,
                                                int* __restrict__ bsum, int n) {
    __shared__ int ss[256];
    int t = threadIdx.x;
    int base = blockIdx.x * 4096 + t * 16;
    int v[16]; int s = 0;
#pragma unroll
    for (int q = 0; q < 16; q++) { v[q] = (base + q < n) ? cnt[base + q] : 0; s += v[q]; }
    ss[t] = s;
    __syncthreads();
    for (int d = 1; d < 256; d <<= 1) {
        int x = (t >= d) ? ss[t - d] : 0;
        __syncthreads();
        ss[t] += x;
        __syncthreads();
    }
    int pre = (t == 0) ? 0 : ss[t - 1];
    if (t == 255) bsum[blockIdx.x] = ss[255];
    int run = pre;
#pragma unroll
    for (int q = 0; q < 16; q++) { if (base + q < n) excl[base + q] = run; run += v[q]; }
}

__global__ __launch_bounds__(256) void k_scanB(int* __restrict__ bsum, int nb) {
    __shared__ int ss[256];
    int t = threadIdx.x;
    int v[8]; int s = 0;
#pragma unroll
    for (int q = 0; q < 8; q++) {
        int idx = t * 8 + q;
        v[q] = (idx < nb) ? bsum[idx] : 0; s += v[q];
    }
    ss[t] = s;
    __syncthreads();
    for (int d = 1; d < 256; d <<= 1) {
        int x = (t >= d) ? ss[t - d] : 0;
        __syncthreads();
        ss[t] += x;
        __syncthreads();
    }
    int run = (t == 0) ? 0 : ss[t - 1];
#pragma unroll
    for (int q = 0; q < 8; q++) {
        int idx = t * 8 + q;
        if (idx < nb) bsum[idx] = run;
        run += v[q];
    }
}

__global__ void k_scanC4(int* __restrict__ gpos, const int* __restrict__ bsum, int n) {
    int i = blockIdx.x * 256 + threadIdx.x;
    if (i < n) gpos[i] += bsum[i >> 12];
}

// ---- pass 1c: place edges into ebuf, bucket-grouped (782 cursors) ----------
// ebuf entry: {src | dstloc<<17, w_f32}
__global__ __launch_bounds__(256) void k_place(const int* __restrict__ ei,
                                               const float* __restrict__ w,
                                               const int* __restrict__ gpos,
                                               int2* __restrict__ ebuf,
                                               int E, int K, int W, int CHv) {
    extern __shared__ int lc[];                // K cursors
    int wg = blockIdx.x, t = threadIdx.x;
    for (int b = t; b < K; b += 256) lc[b] = gpos[(size_t)b * W + wg];
    __syncthreads();
    int j0 = wg * CHv;
    int j1 = min(j0 + CHv, E);
    for (int j = j0 + t; j < j1; j += 256) {
        int s = ei[j], d = ei[E + j];
        float wv = w[j];
        int pos = atomicAdd(&lc[d >> BSH], 1);
        ebuf[pos] = make_int2(s | ((d & (NB - 1)) << 17), __float_as_int(wv));
    }
}

// ---- fine sort: per bucket, sort by (src-chunk, dstloc); emit epack2 +
//      fine CSR rowfine + dinv. All-LDS two-pass sort, coalesced output. -----
__global__ __launch_bounds__(512) void k_sortfine(const int* __restrict__ gcnt,
                                                  const int2* __restrict__ ebuf,
                                                  unsigned* __restrict__ epack2,
                                                  int* __restrict__ rowfine,
                                                  float* __restrict__ dinv,
                                                  int W, int NCH, int E, int K, int N) {
    __shared__ int2 ls[CAP];
    __shared__ unsigned ls2[CAP];
    __shared__ int lh[NKMAX];
    __shared__ int lc[NKMAX];
    __shared__ int ss[512];
    __shared__ float wsum[NB];
    int b = blockIdx.x, t = threadIdx.x;
    int base = gcnt[(size_t)b * W];
    int next = (b + 1 < K) ? gcnt[(size_t)(b + 1) * W] : E;
    int cnt = next - base;
    int nk = NCH * NB;
    for (int i = t; i < nk; i += 512) lh[i] = 0;
    if (t < NB) wsum[t] = 1.0f;                // self-loop weight
    __syncthreads();
    bool fits = cnt <= CAP;
    for (int i = t; i < cnt; i += 512) {       // hist + stage + weight sums
        int2 e = ebuf[base + i];
        if (fits) ls[i] = e;
        int src = e.x & 0x1FFFF, dl = (e.x >> 17) & (NB - 1);
        atomicAdd(&lh[(src >> CSH) * NB + dl], 1);
        atomicAdd(&wsum[dl], __int_as_float(e.y));
    }
    __syncthreads();
    {   // exclusive scan of lh[0..nk) -> lc
        int v[4]; int s = 0;
#pragma unroll
        for (int q = 0; q < 4; q++) {
            int idx = t * 4 + q;
            v[q] = (idx < nk) ? lh[idx] : 0; s += v[q];
        }
        ss[t] = s;
        __syncthreads();
        for (int d = 1; d < 512; d <<= 1) {
            int x = (t >= d) ? ss[t - d] : 0;
            __syncthreads();
            ss[t] += x;
            __syncthreads();
        }
        int run = (t == 0) ? 0 : ss[t - 1];
#pragma unroll
        for (int q = 0; q < 4; q++) {
            int idx = t * 4 + q;
            if (idx < nk) lc[idx] = run;
            run += v[q];
        }
    }
    __syncthreads();
    for (int i = t; i < nk; i += 512)          // fine CSR (before cursors move)
        rowfine[(size_t)b * nk + i] = base + lc[i];
    __syncthreads();
    if (fits) {
        for (int i = t; i < cnt; i += 512) {   // scatter within LDS
            int2 e = ls[i];
            int src = e.x & 0x1FFFF, dl = (e.x >> 17) & (NB - 1);
            int pos = atomicAdd(&lc[(src >> CSH) * NB + dl], 1);
            ls2[pos] = enc_edge(src, __int_as_float(e.y));
        }
        __syncthreads();
        for (int i = t; i < cnt; i += 512)     // coalesced 4B out
            epack2[base + i] = ls2[i];
    } else {                                   // overflow fallback (rare)
        for (int i = t; i < cnt; i += 512) {
            int2 e = ebuf[base + i];
            int src = e.x & 0x1FFFF, dl = (e.x >> 17) & (NB - 1);
            int pos = atomicAdd(&lc[(src >> CSH) * NB + dl], 1);
            epack2[base + pos] = enc_edge(src, __int_as_float(e.y));
        }
    }
    if (t < NB) {
        int node = b * NB + t;
        if (node < N) dinv[node] = rsqrtf(wsum[t]);
    }
    if (b == 0 && t == 0) rowfine[(size_t)K * nk] = E;   // sentinel
}

// ---- GEMM1 (MFMA bf16): h1b[N,128] = dinv[.] * (x[N,256] @ W1) -------------
#define XS_LD 36
#define WT_LD 260
__global__ __launch_bounds__(256) void k_gemm1(const float* __restrict__ x,
                                               const unsigned short* __restrict__ w1t,
                                               const float* __restrict__ dinv,
                                               unsigned short* __restrict__ h1b, int n) {
    __shared__ __align__(16) unsigned short wt[HID_C * WT_LD];
    __shared__ __align__(16) unsigned short xs[64 * XS_LD];
    int tid  = threadIdx.x;
    int row0 = blockIdx.x * 64;
    for (int it = 0; it < 16; it++) {
        int idx = it * 256 + tid;
        int c = idx >> 5, kc = idx & 31;
        uint4 v = *(const uint4*)(w1t + (size_t)c * IN_C + kc * 8);
        uint2* dst = (uint2*)(wt + c * WT_LD + kc * 8);
        dst[0] = make_uint2(v.x, v.y);
        dst[1] = make_uint2(v.z, v.w);
    }
    int wv = tid >> 6, ln = tid & 63;
    int m = ln & 15, quad = ln >> 4;
    float4v acc[8];
#pragma unroll
    for (int ct = 0; ct < 8; ct++) acc[ct] = (float4v){0.f, 0.f, 0.f, 0.f};

    for (int k0 = 0; k0 < IN_C; k0 += 32) {
        __syncthreads();
        {
            int r = tid >> 2, s4 = tid & 3;
            int gr = row0 + r; if (gr >= n) gr = n - 1;
            const float4* px = (const float4*)(x + (size_t)gr * IN_C + k0 + s4 * 8);
            float4 a = px[0], bq = px[1];
            uint2* d = (uint2*)(xs + r * XS_LD + s4 * 8);
            d[0] = make_uint2(pk2(a.x, a.y), pk2(a.z, a.w));
            d[1] = make_uint2(pk2(bq.x, bq.y), pk2(bq.z, bq.w));
        }
        __syncthreads();
        union { uint2 u[2]; short8 v; } af;
        const uint2* pa = (const uint2*)(xs + (wv * 16 + m) * XS_LD + quad * 8);
        af.u[0] = pa[0]; af.u[1] = pa[1];
#pragma unroll
        for (int ct = 0; ct < 8; ct++) {
            union { uint2 u[2]; short8 v; } bf;
            const uint2* pb = (const uint2*)(wt + (ct * 16 + m) * WT_LD + k0 + quad * 8);
            bf.u[0] = pb[0]; bf.u[1] = pb[1];
            acc[ct] = __builtin_amdgcn_mfma_f32_16x16x32_bf16(af.v, bf.v, acc[ct], 0, 0, 0);
        }
    }
    __syncthreads();
    float4 dv = *(const float4*)(dinv + row0 + wv * 16 + quad * 4);
    const float* dvf = (const float*)&dv;
    unsigned short* ot = wt;
#pragma unroll
    for (int ct = 0; ct < 8; ct++)
#pragma unroll
        for (int r = 0; r < 4; r++)
            ot[(wv * 16 + quad * 4 + r) * 136 + ct * 16 + m] = f2bf(acc[ct][r] * dvf[r]);
    __syncthreads();
#pragma unroll
    for (int p = 0; p < 4; p++) {
        int idx = p * 256 + tid;
        int r = idx >> 4, c8 = idx & 15;
        if (row0 + r < n)
            *(uint4*)(h1b + (size_t)(row0 + r) * HID_C + c8 * 8) =
                *(const uint4*)(ot + r * 136 + c8 * 8);
    }
}

// ---- layer-1 aggregation + fused gemm2: PURE WALK (no LDS, no barriers) ----
// 782 blocks x 8 waves (24 waves/CU). Wave owns 16 dsts; quad (16 lanes)
// walks one dst's runs across the NCH chunk segments with dwordx4 gathers
// (L2-hit via chunk cohort). acc au[4][8] statically indexed -> registers.
__global__ __launch_bounds__(512, 8) void k_agg1(const int* __restrict__ rowfine,
                                                 const unsigned* __restrict__ epack2,
                                                 const unsigned short* __restrict__ h1b,
                                                 const float* __restrict__ dinv,
                                                 const float* __restrict__ b1,
                                                 const float* __restrict__ W2,
                                                 float* __restrict__ h2,
                                                 int NCH, int K, int N) {
    int b = blockIdx.x, t = threadIdx.x;
    int wv = t >> 6, lane = t & 63;
    int g = lane >> 4, c16 = lane & 15;
    int nk = NCH * NB;
    const int* rfb = rowfine + (size_t)b * nk;
    float au[4][8];
#pragma unroll
    for (int u = 0; u < 4; u++)
#pragma unroll
        for (int k = 0; k < 8; k++) au[u][k] = 0.f;

#pragma unroll
    for (int u = 0; u < 4; u++) {
        int d = wv * 16 + u * 4 + g;
        for (int ch = 0; ch < NCH; ch++) {
            int jb = rfb[ch * NB + d];
            int je = rfb[ch * NB + d + 1];     // contiguous across segs/buckets
            for (int j = jb; j < je; j++) {
                unsigned rec = epack2[j];      // quad-uniform, L1-hot
                int s; float w;
                dec_edge(rec, s, w);
                uint4 p = *(const uint4*)(h1b + ((size_t)s << 7) + c16 * 8);
                au[u][0] = fmaf(w, bl(p.x), au[u][0]);
                au[u][1] = fmaf(w, bh(p.x), au[u][1]);
                au[u][2] = fmaf(w, bl(p.y), au[u][2]);
                au[u][3] = fmaf(w, bh(p.y), au[u][3]);
                au[u][4] = fmaf(w, bl(p.z), au[u][4]);
                au[u][5] = fmaf(w, bh(p.z), au[u][5]);
                au[u][6] = fmaf(w, bl(p.w), au[u][6]);
                au[u][7] = fmaf(w, bh(p.w), au[u][7]);
            }
        }
    }
    // epilogue: +self, *dinv, +b1, relu, W2 dot, quad butterfly -> h2'
    float4 b1a = *(const float4*)(b1 + c16 * 8);
    float4 b1b = *(const float4*)(b1 + c16 * 8 + 4);
    const float4* wp = (const float4*)(W2 + c16 * 16);
    float4 w0 = wp[0], w1 = wp[1], w2 = wp[2], w3 = wp[3];
#pragma unroll
    for (int u = 0; u < 4; u++) {
        int d = wv * 16 + u * 4 + g;
        int node = b * NB + d;
        bool valid = node < N;
        float di = valid ? dinv[node] : 0.f;
        uint4 sp = make_uint4(0, 0, 0, 0);
        if (valid) sp = *(const uint4*)(h1b + ((size_t)node << 7) + c16 * 8);
        float e0 = fmaxf(fmaf(di, au[u][0] + bl(sp.x), b1a.x), 0.f);
        float e1 = fmaxf(fmaf(di, au[u][1] + bh(sp.x), b1a.y), 0.f);
        float e2 = fmaxf(fmaf(di, au[u][2] + bl(sp.y), b1a.z), 0.f);
        float e3 = fmaxf(fmaf(di, au[u][3] + bh(sp.y), b1a.w), 0.f);
        float e4 = fmaxf(fmaf(di, au[u][4] + bl(sp.z), b1b.x), 0.f);
        float e5 = fmaxf(fmaf(di, au[u][5] + bh(sp.z), b1b.y), 0.f);
        float e6 = fmaxf(fmaf(di, au[u][6] + bl(sp.w), b1b.z), 0.f);
        float e7 = fmaxf(fmaf(di, au[u][7] + bh(sp.w), b1b.w), 0.f);
        float s0 = e0 * w0.x + e1 * w0.z + e2 * w1.x + e3 * w1.z
                 + e4 * w2.x + e5 * w2.z + e6 * w3.x + e7 * w3.z;
        float s1 = e0 * w0.y + e1 * w0.w + e2 * w1.y + e3 * w1.w
                 + e4 * w2.y + e5 * w2.w + e6 * w3.y + e7 * w3.w;
#pragma unroll
        for (int dd = 1; dd < 16; dd <<= 1) {
            s0 += __shfl_xor(s0, dd);
            s1 += __shfl_xor(s1, dd);
        }
        if (c16 == 0 && valid)
            ((float2*)h2)[node] = make_float2(di * s0, di * s1);
    }
}

// ---- layer-2 aggregation: walk over fine CSR, 2 lanes/dst ------------------
__global__ __launch_bounds__(256) void k_agg2(const int* __restrict__ rowfine,
                                              const unsigned* __restrict__ epack2,
                                              const float* __restrict__ h2,
                                              const float* __restrict__ dinv,
                                              const float* __restrict__ b2,
                                              float* __restrict__ out,
                                              int NCH, int K, int N) {
    __shared__ float a2[NB * 2];
    int b = blockIdx.x, t = threadIdx.x;
    int d = t & 127, half = t >> 7;
    int nk = NCH * NB;
    const int* rfb = rowfine + (size_t)b * nk;
    float sx = 0.f, sy = 0.f;
    for (int ch = half; ch < NCH; ch += 2) {
        int jb = rfb[ch * NB + d];
        int je = rfb[ch * NB + d + 1];
        for (int j = jb; j < je; j++) {
            unsigned rec = epack2[j];
            int s; float w;
            dec_edge(rec, s, w);
            float2 v = ((const float2*)h2)[s];
            sx = fmaf(w, v.x, sx);
            sy = fmaf(w, v.y, sy);
        }
    }
    if (half == 1) { a2[d * 2] = sx; a2[d * 2 + 1] = sy; }
    __syncthreads();
    if (half == 0) {
        int node = b * NB + d;
        if (node < N) {
            float di = dinv[node];
            float2 hv = ((const float2*)h2)[node];   // already dinv*H2
            sx += a2[d * 2]; sy += a2[d * 2 + 1];
            ((float2*)out)[node] = make_float2(b2[0] + di * (sx + hv.x),
                                               b2[1] + di * (sy + hv.y));
        }
    }
}

static inline size_t algn16(size_t v) { return (v + 15) & ~(size_t)15; }

extern "C" void kernel_launch(void* const* d_in, const int* in_sizes, int n_in,
                              void* d_out, int out_size, void* d_ws, size_t ws_size,
                              hipStream_t stream) {
    const float* x  = (const float*)d_in[0];
    const int*   ei = (const int*)d_in[1];   // [2,E] int32
    const float* ew = (const float*)d_in[2];
    const float* W1 = (const float*)d_in[3];
    const float* b1 = (const float*)d_in[4];
    const float* W2 = (const float*)d_in[5];
    const float* b2 = (const float*)d_in[6];
    float* out = (float*)d_out;

    int N = in_sizes[0] / IN_C;
    int E = in_sizes[2];
    int K = (N + NB - 1) >> BSH;             // buckets (782)
    int NCH = (N + (1 << CSH) - 1) >> CSH;   // src chunks (13)
    int nk = NCH * NB;                       // fine keys per bucket (1664)
    int W = 256;                             // pass-1 workgroups
    int CHv = (E + W - 1) / W;
    int KW = K * W;                          // coarse hist size (~200k)

    char* ws = (char*)d_ws;
    float* dinv    = (float*)ws; ws += algn16((size_t)N * 4);
    int*   gcnt    = (int*)ws;   ws += algn16((size_t)KW * 4);
    int*   bsum    = (int*)ws;   ws += 8192;
    int*   rowfine = (int*)ws;   ws += algn16(((size_t)K * nk + 1) * 4);
    unsigned* epack2 = (unsigned*)ws; ws += algn16((size_t)E * 4);
    // ebuf (E*8) and h1b (N*256) alias: sortfine consumes ebuf before gemm1
    size_t big = (size_t)E * 8;
    size_t h1sz = (size_t)N * HID_C * 2;
    if (h1sz > big) big = h1sz;
    int2* ebuf = (int2*)ws;
    unsigned short* h1b = (unsigned short*)ws; ws += algn16(big);
    unsigned short* w1t = (unsigned short*)ws; ws += algn16((size_t)HID_C * IN_C * 2);
    float* h2      = (float*)ws; ws += algn16((size_t)N * OUT_C * 4);

    int nb_s4 = (KW + 4095) / 4096;          // 49
    int nb_sc = (KW + 255) / 256;
    size_t lds_k = (size_t)K * 4;            // ~3.1 KB dynamic LDS

    k_wT      <<<(HID_C * IN_C + 255) / 256, 256, 0, stream>>>(W1, w1t);
    k_count   <<<W, 256, lds_k, stream>>>(ei, gcnt, E, K, W, CHv);
    k_scanA4  <<<nb_s4, 256, 0, stream>>>(gcnt, gcnt, bsum, KW);
    k_scanB   <<<1, 256, 0, stream>>>(bsum, nb_s4);
    k_scanC4  <<<nb_sc, 256, 0, stream>>>(gcnt, bsum, KW);
    k_place   <<<W, 256, lds_k, stream>>>(ei, ew, gcnt, ebuf, E, K, W, CHv);
    k_sortfine<<<K, 512, 0, stream>>>(gcnt, ebuf, epack2, rowfine, dinv, W, NCH, E, K, N);
    k_gemm1   <<<(N + 63) / 64, 256, 0, stream>>>(x, w1t, dinv, h1b, N);
    k_agg1    <<<K, 512, 0, stream>>>(rowfine, epack2, h1b, dinv, b1, W2, h2, NCH, K, N);
    k_agg2    <<<K, 256, 0, stream>>>(rowfine, epack2, h2, dinv, b2, out, NCH, K, N);
}

// Round 5
// 531.217 us; speedup vs baseline: 5.7596x; 1.0362x over previous
//
#include <hip/hip_runtime.h>
#include <hip/hip_fp16.h>

#define IN_C  256
#define HID_C 128
#define OUT_C 2
#define BSH   7                    // nodes per bucket = 128
#define NB    128
#define CSH   13                   // src chunk = 8192 rows (2MB L2 window)
#define MAXNCH 16                  // max chunks (N < 131072)
#define NKMAX  (MAXNCH * NB)       // max fine keys per bucket (2048)
#define CAP    4608                // sortfine LDS staging capacity (mean 4092)

typedef __attribute__((ext_vector_type(8))) short short8;
typedef __attribute__((ext_vector_type(4))) float float4v;

__device__ __forceinline__ unsigned short f2bf(float f) {   // RNE float->bf16
    unsigned u = __float_as_uint(f);
    unsigned r = 0x7fffu + ((u >> 16) & 1u);
    return (unsigned short)((u + r) >> 16);
}
__device__ __forceinline__ unsigned pk2(float a, float b) {
    return (unsigned)f2bf(a) | ((unsigned)f2bf(b) << 16);
}
// packed edge: bits[16:0]=src (N<2^17), bits[31:17]=fp16(w) sans sign (w>=0)
__device__ __forceinline__ unsigned enc_edge(int src, float w) {
    unsigned h = (unsigned)(__half_as_ushort(__float2half(w)) & 0x7FFF);
    return (h << 17) | (unsigned)src;
}
__device__ __forceinline__ void dec_edge(unsigned rec, int& s, float& w) {
    s = (int)(rec & 0x1FFFFu);
    __half hh;
    *(unsigned short*)&hh = (unsigned short)(rec >> 17);
    w = __half2float(hh);
}
__device__ __forceinline__ float bl(unsigned u) { return __uint_as_float(u << 16); }
__device__ __forceinline__ float bh(unsigned u) { return __uint_as_float(u & 0xffff0000u); }

// ---- W1^T bf16 precompute --------------------------------------------------
__global__ void k_wT(const float* __restrict__ W1, unsigned short* __restrict__ w1t) {
    int i = blockIdx.x * 256 + threadIdx.x;
    if (i >= HID_C * IN_C) return;
    int c = i >> 8, k = i & 255;
    w1t[i] = f2bf(W1[(size_t)k * HID_C + c]);
}

// ---- pass 1a: per-wg bucket histogram -> gcnt[b*W + w] (782 keys, cheap) ---
__global__ __launch_bounds__(256) void k_count(const int* __restrict__ ei,
                                               int* __restrict__ gcnt,
                                               int E, int K, int W, int CHv) {
    extern __shared__ int lh[];                // K ints (~3.1 KB)
    int w = blockIdx.x, t = threadIdx.x;
    for (int b = t; b < K; b += 256) lh[b] = 0;
    __syncthreads();
    int j0 = w * CHv;
    int j1 = min(j0 + CHv, E);
    for (int j = j0 + t; j < j1; j += 256)
        atomicAdd(&lh[ei[E + j] >> BSH], 1);
    __syncthreads();
    for (int b = t; b < K; b += 256) gcnt[(size_t)b * W + w] = lh[b];
}

// ---- scan: 4096 elems/block ------------------------------------------------
__global__ __launch_bounds__(256) void k_scanA4(const int* __restrict__ cnt,
                                                int* __restrict__ excl,
                                                int* __restrict__ bsum, int n) {
    __shared__ int ss[256];
    int t = threadIdx.x;
    int base = blockIdx.x * 4096 + t * 16;
    int v[16]; int s = 0;
#pragma unroll
    for (int q = 0; q < 16; q++) { v[q] = (base + q < n) ? cnt[base + q] : 0; s += v[q]; }
    ss[t] = s;
    __syncthreads();
    for (int d = 1; d < 256; d <<= 1) {
        int x = (t >= d) ? ss[t - d] : 0;
        __syncthreads();
        ss[t] += x;
        __syncthreads();
    }
    int pre = (t == 0) ? 0 : ss[t - 1];
    if (t == 255) bsum[blockIdx.x] = ss[255];
    int run = pre;
#pragma unroll
    for (int q = 0; q < 16; q++) { if (base + q < n) excl[base + q] = run; run += v[q]; }
}

__global__ __launch_bounds__(256) void k_scanB(int* __restrict__ bsum, int nb) {
    __shared__ int ss[256];
    int t = threadIdx.x;
    int v[8]; int s = 0;
#pragma unroll
    for (int q = 0; q < 8; q++) {
        int idx = t * 8 + q;
        v[q] = (idx < nb) ? bsum[idx] : 0; s += v[q];
    }
    ss[t] = s;
    __syncthreads();
    for (int d = 1; d < 256; d <<= 1) {
        int x = (t >= d) ? ss[t - d] : 0;
        __syncthreads();
        ss[t] += x;
        __syncthreads();
    }
    int run = (t == 0) ? 0 : ss[t - 1];
#pragma unroll
    for (int q = 0; q < 8; q++) {
        int idx = t * 8 + q;
        if (idx < nb) bsum[idx] = run;
        run += v[q];
    }
}

__global__ void k_scanC4(int* __restrict__ gpos, const int* __restrict__ bsum, int n) {
    int i = blockIdx.x * 256 + threadIdx.x;
    if (i < n) gpos[i] += bsum[i >> 12];
}

// ---- pass 1c: place edges into ebuf, bucket-grouped (782 cursors) ----------
// ebuf entry: {src | dstloc<<17, w_f32}
__global__ __launch_bounds__(256) void k_place(const int* __restrict__ ei,
                                               const float* __restrict__ w,
                                               const int* __restrict__ gpos,
                                               int2* __restrict__ ebuf,
                                               int E, int K, int W, int CHv) {
    extern __shared__ int lc[];                // K cursors
    int wg = blockIdx.x, t = threadIdx.x;
    for (int b = t; b < K; b += 256) lc[b] = gpos[(size_t)b * W + wg];
    __syncthreads();
    int j0 = wg * CHv;
    int j1 = min(j0 + CHv, E);
    for (int j = j0 + t; j < j1; j += 256) {
        int s = ei[j], d = ei[E + j];
        float wv = w[j];
        int pos = atomicAdd(&lc[d >> BSH], 1);
        ebuf[pos] = make_int2(s | ((d & (NB - 1)) << 17), __float_as_int(wv));
    }
}

// ---- fine sort: per bucket, sort by (src-chunk, dstloc); emit epack2 +
//      fine CSR rowfine + dinv. All-LDS two-pass sort, coalesced output. -----
__global__ __launch_bounds__(512) void k_sortfine(const int* __restrict__ gcnt,
                                                  const int2* __restrict__ ebuf,
                                                  unsigned* __restrict__ epack2,
                                                  int* __restrict__ rowfine,
                                                  float* __restrict__ dinv,
                                                  int W, int NCH, int E, int K, int N) {
    __shared__ int2 ls[CAP];
    __shared__ unsigned ls2[CAP];
    __shared__ int lh[NKMAX];
    __shared__ int lc[NKMAX];
    __shared__ int ss[512];
    __shared__ float wsum[NB];
    int b = blockIdx.x, t = threadIdx.x;
    int base = gcnt[(size_t)b * W];
    int next = (b + 1 < K) ? gcnt[(size_t)(b + 1) * W] : E;
    int cnt = next - base;
    int nk = NCH * NB;
    for (int i = t; i < nk; i += 512) lh[i] = 0;
    if (t < NB) wsum[t] = 1.0f;                // self-loop weight
    __syncthreads();
    bool fits = cnt <= CAP;
    for (int i = t; i < cnt; i += 512) {       // hist + stage + weight sums
        int2 e = ebuf[base + i];
        if (fits) ls[i] = e;
        int src = e.x & 0x1FFFF, dl = (e.x >> 17) & (NB - 1);
        atomicAdd(&lh[(src >> CSH) * NB + dl], 1);
        atomicAdd(&wsum[dl], __int_as_float(e.y));
    }
    __syncthreads();
    {   // exclusive scan of lh[0..nk) -> lc
        int v[4]; int s = 0;
#pragma unroll
        for (int q = 0; q < 4; q++) {
            int idx = t * 4 + q;
            v[q] = (idx < nk) ? lh[idx] : 0; s += v[q];
        }
        ss[t] = s;
        __syncthreads();
        for (int d = 1; d < 512; d <<= 1) {
            int x = (t >= d) ? ss[t - d] : 0;
            __syncthreads();
            ss[t] += x;
            __syncthreads();
        }
        int run = (t == 0) ? 0 : ss[t - 1];
#pragma unroll
        for (int q = 0; q < 4; q++) {
            int idx = t * 4 + q;
            if (idx < nk) lc[idx] = run;
            run += v[q];
        }
    }
    __syncthreads();
    for (int i = t; i < nk; i += 512)          // fine CSR (before cursors move)
        rowfine[(size_t)b * nk + i] = base + lc[i];
    __syncthreads();
    if (fits) {
        for (int i = t; i < cnt; i += 512) {   // scatter within LDS
            int2 e = ls[i];
            int src = e.x & 0x1FFFF, dl = (e.x >> 17) & (NB - 1);
            int pos = atomicAdd(&lc[(src >> CSH) * NB + dl], 1);
            ls2[pos] = enc_edge(src, __int_as_float(e.y));
        }
        __syncthreads();
        for (int i = t; i < cnt; i += 512)     // coalesced 4B out
            epack2[base + i] = ls2[i];
    } else {                                   // overflow fallback (rare)
        for (int i = t; i < cnt; i += 512) {
            int2 e = ebuf[base + i];
            int src = e.x & 0x1FFFF, dl = (e.x >> 17) & (NB - 1);
            int pos = atomicAdd(&lc[(src >> CSH) * NB + dl], 1);
            epack2[base + pos] = enc_edge(src, __int_as_float(e.y));
        }
    }
    if (t < NB) {
        int node = b * NB + t;
        if (node < N) dinv[node] = rsqrtf(wsum[t]);
    }
    if (b == 0 && t == 0) rowfine[(size_t)K * nk] = E;   // sentinel
}

// ---- GEMM1 (MFMA bf16): h1b[N,128] = dinv[.] * (x[N,256] @ W1) -------------
#define XS_LD 36
#define WT_LD 260
__global__ __launch_bounds__(256) void k_gemm1(const float* __restrict__ x,
                                               const unsigned short* __restrict__ w1t,
                                               const float* __restrict__ dinv,
                                               unsigned short* __restrict__ h1b, int n) {
    __shared__ __align__(16) unsigned short wt[HID_C * WT_LD];
    __shared__ __align__(16) unsigned short xs[64 * XS_LD];
    int tid  = threadIdx.x;
    int row0 = blockIdx.x * 64;
    for (int it = 0; it < 16; it++) {
        int idx = it * 256 + tid;
        int c = idx >> 5, kc = idx & 31;
        uint4 v = *(const uint4*)(w1t + (size_t)c * IN_C + kc * 8);
        uint2* dst = (uint2*)(wt + c * WT_LD + kc * 8);
        dst[0] = make_uint2(v.x, v.y);
        dst[1] = make_uint2(v.z, v.w);
    }
    int wv = tid >> 6, ln = tid & 63;
    int m = ln & 15, quad = ln >> 4;
    float4v acc[8];
#pragma unroll
    for (int ct = 0; ct < 8; ct++) acc[ct] = (float4v){0.f, 0.f, 0.f, 0.f};

    for (int k0 = 0; k0 < IN_C; k0 += 32) {
        __syncthreads();
        {
            int r = tid >> 2, s4 = tid & 3;
            int gr = row0 + r; if (gr >= n) gr = n - 1;
            const float4* px = (const float4*)(x + (size_t)gr * IN_C + k0 + s4 * 8);
            float4 a = px[0], bq = px[1];
            uint2* d = (uint2*)(xs + r * XS_LD + s4 * 8);
            d[0] = make_uint2(pk2(a.x, a.y), pk2(a.z, a.w));
            d[1] = make_uint2(pk2(bq.x, bq.y), pk2(bq.z, bq.w));
        }
        __syncthreads();
        union { uint2 u[2]; short8 v; } af;
        const uint2* pa = (const uint2*)(xs + (wv * 16 + m) * XS_LD + quad * 8);
        af.u[0] = pa[0]; af.u[1] = pa[1];
#pragma unroll
        for (int ct = 0; ct < 8; ct++) {
            union { uint2 u[2]; short8 v; } bf;
            const uint2* pb = (const uint2*)(wt + (ct * 16 + m) * WT_LD + k0 + quad * 8);
            bf.u[0] = pb[0]; bf.u[1] = pb[1];
            acc[ct] = __builtin_amdgcn_mfma_f32_16x16x32_bf16(af.v, bf.v, acc[ct], 0, 0, 0);
        }
    }
    __syncthreads();
    float4 dv = *(const float4*)(dinv + row0 + wv * 16 + quad * 4);
    const float* dvf = (const float*)&dv;
    unsigned short* ot = wt;
#pragma unroll
    for (int ct = 0; ct < 8; ct++)
#pragma unroll
        for (int r = 0; r < 4; r++)
            ot[(wv * 16 + quad * 4 + r) * 136 + ct * 16 + m] = f2bf(acc[ct][r] * dvf[r]);
    __syncthreads();
#pragma unroll
    for (int p = 0; p < 4; p++) {
        int idx = p * 256 + tid;
        int r = idx >> 4, c8 = idx & 15;
        if (row0 + r < n)
            *(uint4*)(h1b + (size_t)(row0 + r) * HID_C + c8 * 8) =
                *(const uint4*)(ot + r * 136 + c8 * 8);
    }
}

// ---- layer-1 aggregation + fused gemm2: pure walk, CHUNK-OUTER -------------
// 782 blocks x 8 waves, all co-resident (<=64 VGPR -> 4 blocks/CU).
// Outermost loop = src chunk: every resident block gathers from the same
// ~2MB h1b window at any instant (L2-hit cohort, validated R2/R3).
// Wave owns 16 dsts via 4 quads x 4 dst-slots; acc au[4][8] lives across
// the chunk loop (statically indexed -> registers).
__global__ __launch_bounds__(512, 8) void k_agg1(const int* __restrict__ rowfine,
                                                 const unsigned* __restrict__ epack2,
                                                 const unsigned short* __restrict__ h1b,
                                                 const float* __restrict__ dinv,
                                                 const float* __restrict__ b1,
                                                 const float* __restrict__ W2,
                                                 float* __restrict__ h2,
                                                 int NCH, int K, int N) {
    int b = blockIdx.x, t = threadIdx.x;
    int wv = t >> 6, lane = t & 63;
    int g = lane >> 4, c16 = lane & 15;
    int nk = NCH * NB;
    const int* rfb = rowfine + (size_t)b * nk;
    float au[4][8];
#pragma unroll
    for (int u = 0; u < 4; u++)
#pragma unroll
        for (int k = 0; k < 8; k++) au[u][k] = 0.f;

    for (int ch = 0; ch < NCH; ch++) {         // chunk = outermost time axis
        const int* rf = rfb + ch * NB;
#pragma unroll
        for (int u = 0; u < 4; u++) {
            int d = wv * 16 + u * 4 + g;
            int jb = rf[d], je = rf[d + 1];    // contiguous across keys
            for (int j = jb; j < je; j++) {
                unsigned rec = epack2[j];      // quad-uniform, L1-hot
                int s; float w;
                dec_edge(rec, s, w);
                uint4 p = *(const uint4*)(h1b + ((size_t)s << 7) + c16 * 8);
                au[u][0] = fmaf(w, bl(p.x), au[u][0]);
                au[u][1] = fmaf(w, bh(p.x), au[u][1]);
                au[u][2] = fmaf(w, bl(p.y), au[u][2]);
                au[u][3] = fmaf(w, bh(p.y), au[u][3]);
                au[u][4] = fmaf(w, bl(p.z), au[u][4]);
                au[u][5] = fmaf(w, bh(p.z), au[u][5]);
                au[u][6] = fmaf(w, bl(p.w), au[u][6]);
                au[u][7] = fmaf(w, bh(p.w), au[u][7]);
            }
        }
    }
    // epilogue: +self, *dinv, +b1, relu, W2 dot, quad butterfly -> h2'
    float4 b1a = *(const float4*)(b1 + c16 * 8);
    float4 b1b = *(const float4*)(b1 + c16 * 8 + 4);
    const float4* wp = (const float4*)(W2 + c16 * 16);
    float4 w0 = wp[0], w1 = wp[1], w2 = wp[2], w3 = wp[3];
#pragma unroll
    for (int u = 0; u < 4; u++) {
        int d = wv * 16 + u * 4 + g;
        int node = b * NB + d;
        bool valid = node < N;
        float di = valid ? dinv[node] : 0.f;
        uint4 sp = make_uint4(0, 0, 0, 0);
        if (valid) sp = *(const uint4*)(h1b + ((size_t)node << 7) + c16 * 8);
        float e0 = fmaxf(fmaf(di, au[u][0] + bl(sp.x), b1a.x), 0.f);
        float e1 = fmaxf(fmaf(di, au[u][1] + bh(sp.x), b1a.y), 0.f);
        float e2 = fmaxf(fmaf(di, au[u][2] + bl(sp.y), b1a.z), 0.f);
        float e3 = fmaxf(fmaf(di, au[u][3] + bh(sp.y), b1a.w), 0.f);
        float e4 = fmaxf(fmaf(di, au[u][4] + bl(sp.z), b1b.x), 0.f);
        float e5 = fmaxf(fmaf(di, au[u][5] + bh(sp.z), b1b.y), 0.f);
        float e6 = fmaxf(fmaf(di, au[u][6] + bl(sp.w), b1b.z), 0.f);
        float e7 = fmaxf(fmaf(di, au[u][7] + bh(sp.w), b1b.w), 0.f);
        float s0 = e0 * w0.x + e1 * w0.z + e2 * w1.x + e3 * w1.z
                 + e4 * w2.x + e5 * w2.z + e6 * w3.x + e7 * w3.z;
        float s1 = e0 * w0.y + e1 * w0.w + e2 * w1.y + e3 * w1.w
                 + e4 * w2.y + e5 * w2.w + e6 * w3.y + e7 * w3.w;
#pragma unroll
        for (int dd = 1; dd < 16; dd <<= 1) {
            s0 += __shfl_xor(s0, dd);
            s1 += __shfl_xor(s1, dd);
        }
        if (c16 == 0 && valid)
            ((float2*)h2)[node] = make_float2(di * s0, di * s1);
    }
}

// ---- layer-2 aggregation: walk over fine CSR, 2 lanes/dst ------------------
__global__ __launch_bounds__(256) void k_agg2(const int* __restrict__ rowfine,
                                              const unsigned* __restrict__ epack2,
                                              const float* __restrict__ h2,
                                              const float* __restrict__ dinv,
                                              const float* __restrict__ b2,
                                              float* __restrict__ out,
                                              int NCH, int K, int N) {
    __shared__ float a2[NB * 2];
    int b = blockIdx.x, t = threadIdx.x;
    int d = t & 127, half = t >> 7;
    int nk = NCH * NB;
    const int* rfb = rowfine + (size_t)b * nk;
    float sx = 0.f, sy = 0.f;
    for (int ch = half; ch < NCH; ch += 2) {
        int jb = rfb[ch * NB + d];
        int je = rfb[ch * NB + d + 1];
        for (int j = jb; j < je; j++) {
            unsigned rec = epack2[j];
            int s; float w;
            dec_edge(rec, s, w);
            float2 v = ((const float2*)h2)[s];
            sx = fmaf(w, v.x, sx);
            sy = fmaf(w, v.y, sy);
        }
    }
    if (half == 1) { a2[d * 2] = sx; a2[d * 2 + 1] = sy; }
    __syncthreads();
    if (half == 0) {
        int node = b * NB + d;
        if (node < N) {
            float di = dinv[node];
            float2 hv = ((const float2*)h2)[node];   // already dinv*H2
            sx += a2[d * 2]; sy += a2[d * 2 + 1];
            ((float2*)out)[node] = make_float2(b2[0] + di * (sx + hv.x),
                                               b2[1] + di * (sy + hv.y));
        }
    }
}

static inline size_t algn16(size_t v) { return (v + 15) & ~(size_t)15; }

extern "C" void kernel_launch(void* const* d_in, const int* in_sizes, int n_in,
                              void* d_out, int out_size, void* d_ws, size_t ws_size,
                              hipStream_t stream) {
    const float* x  = (const float*)d_in[0];
    const int*   ei = (const int*)d_in[1];   // [2,E] int32
    const float* ew = (const float*)d_in[2];
    const float* W1 = (const float*)d_in[3];
    const float* b1 = (const float*)d_in[4];
    const float* W2 = (const float*)d_in[5];
    const float* b2 = (const float*)d_in[6];
    float* out = (float*)d_out;

    int N = in_sizes[0] / IN_C;
    int E = in_sizes[2];
    int K = (N + NB - 1) >> BSH;             // buckets (782)
    int NCH = (N + (1 << CSH) - 1) >> CSH;   // src chunks (13)
    int nk = NCH * NB;                       // fine keys per bucket (1664)
    int W = 256;                             // pass-1 workgroups
    int CHv = (E + W - 1) / W;
    int KW = K * W;                          // coarse hist size (~200k)

    char* ws = (char*)d_ws;
    float* dinv    = (float*)ws; ws += algn16((size_t)N * 4);
    int*   gcnt    = (int*)ws;   ws += algn16((size_t)KW * 4);
    int*   bsum    = (int*)ws;   ws += 8192;
    int*   rowfine = (int*)ws;   ws += algn16(((size_t)K * nk + 1) * 4);
    unsigned* epack2 = (unsigned*)ws; ws += algn16((size_t)E * 4);
    // ebuf (E*8) and h1b (N*256) alias: sortfine consumes ebuf before gemm1
    size_t big = (size_t)E * 8;
    size_t h1sz = (size_t)N * HID_C * 2;
    if (h1sz > big) big = h1sz;
    int2* ebuf = (int2*)ws;
    unsigned short* h1b = (unsigned short*)ws; ws += algn16(big);
    unsigned short* w1t = (unsigned short*)ws; ws += algn16((size_t)HID_C * IN_C * 2);
    float* h2      = (float*)ws; ws += algn16((size_t)N * OUT_C * 4);

    int nb_s4 = (KW + 4095) / 4096;          // 49
    int nb_sc = (KW + 255) / 256;
    size_t lds_k = (size_t)K * 4;            // ~3.1 KB dynamic LDS

    k_wT      <<<(HID_C * IN_C + 255) / 256, 256, 0, stream>>>(W1, w1t);
    k_count   <<<W, 256, lds_k, stream>>>(ei, gcnt, E, K, W, CHv);
    k_scanA4  <<<nb_s4, 256, 0, stream>>>(gcnt, gcnt, bsum, KW);
    k_scanB   <<<1, 256, 0, stream>>>(bsum, nb_s4);
    k_scanC4  <<<nb_sc, 256, 0, stream>>>(gcnt, bsum, KW);
    k_place   <<<W, 256, lds_k, stream>>>(ei, ew, gcnt, ebuf, E, K, W, CHv);
    k_sortfine<<<K, 512, 0, stream>>>(gcnt, ebuf, epack2, rowfine, dinv, W, NCH, E, K, N);
    k_gemm1   <<<(N + 63) / 64, 256, 0, stream>>>(x, w1t, dinv, h1b, N);
    k_agg1    <<<K, 512, 0, stream>>>(rowfine, epack2, h1b, dinv, b1, W2, h2, NCH, K, N);
    k_agg2    <<<K, 256, 0, stream>>>(rowfine, epack2, h2, dinv, b2, out, NCH, K, N);
}

// Round 6
// 502.997 us; speedup vs baseline: 6.0827x; 1.0561x over previous
//
#include <hip/hip_runtime.h>
#include <hip/hip_fp16.h>

#define IN_C  256
#define HID_C 128
#define OUT_C 2
#define BSH   7                    // nodes per bucket = 128
#define NB    128
#define CSH   13                   // src chunk = 8192 rows (2MB L2 window)
#define MAXNCH 16                  // max chunks (N < 131072)
#define NKMAX  (MAXNCH * NB)       // max fine keys per bucket (2048)
#define CAP    4608                // sortfine LDS staging capacity (mean 4092)

typedef __attribute__((ext_vector_type(8))) short short8;
typedef __attribute__((ext_vector_type(4))) float float4v;

__device__ __forceinline__ unsigned short f2bf(float f) {   // RNE float->bf16
    unsigned u = __float_as_uint(f);
    unsigned r = 0x7fffu + ((u >> 16) & 1u);
    return (unsigned short)((u + r) >> 16);
}
__device__ __forceinline__ unsigned pk2(float a, float b) {
    return (unsigned)f2bf(a) | ((unsigned)f2bf(b) << 16);
}
// packed edge: bits[16:0]=src (N<2^17), bits[31:17]=fp16(w) sans sign (w>=0)
__device__ __forceinline__ unsigned enc_edge(int src, float w) {
    unsigned h = (unsigned)(__half_as_ushort(__float2half(w)) & 0x7FFF);
    return (h << 17) | (unsigned)src;
}
__device__ __forceinline__ void dec_edge(unsigned rec, int& s, float& w) {
    s = (int)(rec & 0x1FFFFu);
    __half hh;
    *(unsigned short*)&hh = (unsigned short)(rec >> 17);
    w = __half2float(hh);
}
__device__ __forceinline__ float bl(unsigned u) { return __uint_as_float(u << 16); }
__device__ __forceinline__ float bh(unsigned u) { return __uint_as_float(u & 0xffff0000u); }
__device__ __forceinline__ void fma8r(float (&a)[8], uint4 p, float w) {
    a[0] = fmaf(w, bl(p.x), a[0]); a[1] = fmaf(w, bh(p.x), a[1]);
    a[2] = fmaf(w, bl(p.y), a[2]); a[3] = fmaf(w, bh(p.y), a[3]);
    a[4] = fmaf(w, bl(p.z), a[4]); a[5] = fmaf(w, bh(p.z), a[5]);
    a[6] = fmaf(w, bl(p.w), a[6]); a[7] = fmaf(w, bh(p.w), a[7]);
}

// ---- W1^T bf16 precompute --------------------------------------------------
__global__ void k_wT(const float* __restrict__ W1, unsigned short* __restrict__ w1t) {
    int i = blockIdx.x * 256 + threadIdx.x;
    if (i >= HID_C * IN_C) return;
    int c = i >> 8, k = i & 255;
    w1t[i] = f2bf(W1[(size_t)k * HID_C + c]);
}

// ---- pass 1a: per-wg bucket histogram -> gcnt[b*W + w] (782 keys, cheap) ---
__global__ __launch_bounds__(256) void k_count(const int* __restrict__ ei,
                                               int* __restrict__ gcnt,
                                               int E, int K, int W, int CHv) {
    extern __shared__ int lh[];                // K ints (~3.1 KB)
    int w = blockIdx.x, t = threadIdx.x;
    for (int b = t; b < K; b += 256) lh[b] = 0;
    __syncthreads();
    int j0 = w * CHv;
    int j1 = min(j0 + CHv, E);
    for (int j = j0 + t; j < j1; j += 256)
        atomicAdd(&lh[ei[E + j] >> BSH], 1);
    __syncthreads();
    for (int b = t; b < K; b += 256) gcnt[(size_t)b * W + w] = lh[b];
}

// ---- scan: 4096 elems/block ------------------------------------------------
__global__ __launch_bounds__(256) void k_scanA4(const int* __restrict__ cnt,
                                                int* __restrict__ excl,
                                                int* __restrict__ bsum, int n) {
    __shared__ int ss[256];
    int t = threadIdx.x;
    int base = blockIdx.x * 4096 + t * 16;
    int v[16]; int s = 0;
#pragma unroll
    for (int q = 0; q < 16; q++) { v[q] = (base + q < n) ? cnt[base + q] : 0; s += v[q]; }
    ss[t] = s;
    __syncthreads();
    for (int d = 1; d < 256; d <<= 1) {
        int x = (t >= d) ? ss[t - d] : 0;
        __syncthreads();
        ss[t] += x;
        __syncthreads();
    }
    int pre = (t == 0) ? 0 : ss[t - 1];
    if (t == 255) bsum[blockIdx.x] = ss[255];
    int run = pre;
#pragma unroll
    for (int q = 0; q < 16; q++) { if (base + q < n) excl[base + q] = run; run += v[q]; }
}

__global__ __launch_bounds__(256) void k_scanB(int* __restrict__ bsum, int nb) {
    __shared__ int ss[256];
    int t = threadIdx.x;
    int v[8]; int s = 0;
#pragma unroll
    for (int q = 0; q < 8; q++) {
        int idx = t * 8 + q;
        v[q] = (idx < nb) ? bsum[idx] : 0; s += v[q];
    }
    ss[t] = s;
    __syncthreads();
    for (int d = 1; d < 256; d <<= 1) {
        int x = (t >= d) ? ss[t - d] : 0;
        __syncthreads();
        ss[t] += x;
        __syncthreads();
    }
    int run = (t == 0) ? 0 : ss[t - 1];
#pragma unroll
    for (int q = 0; q < 8; q++) {
        int idx = t * 8 + q;
        if (idx < nb) bsum[idx] = run;
        run += v[q];
    }
}

// ---- pass 1c: place edges into ebuf, bucket-grouped (782 cursors) ----------
// Reads gcnt (per-wg exclusive within 4096-blocks) + bsum fixup inline.
// ebuf entry: {src | dstloc<<17, w_f32}
__global__ __launch_bounds__(256) void k_place(const int* __restrict__ ei,
                                               const float* __restrict__ w,
                                               const int* __restrict__ gpos,
                                               const int* __restrict__ bsum,
                                               int2* __restrict__ ebuf,
                                               int E, int K, int W, int CHv) {
    extern __shared__ int lc[];                // K cursors
    int wg = blockIdx.x, t = threadIdx.x;
    for (int b = t; b < K; b += 256) {
        size_t i = (size_t)b * W + wg;
        lc[b] = gpos[i] + bsum[i >> 12];
    }
    __syncthreads();
    int j0 = wg * CHv;
    int j1 = min(j0 + CHv, E);
    for (int j = j0 + t; j < j1; j += 256) {
        int s = ei[j], d = ei[E + j];
        float wv = w[j];
        int pos = atomicAdd(&lc[d >> BSH], 1);
        ebuf[pos] = make_int2(s | ((d & (NB - 1)) << 17), __float_as_int(wv));
    }
}

// ---- fine sort: per bucket, sort by (src-chunk, dstloc); emit epack2 +
//      fine CSR rowfine + dinv. All-LDS two-pass sort, coalesced output. -----
__global__ __launch_bounds__(512) void k_sortfine(const int* __restrict__ gcnt,
                                                  const int* __restrict__ bsum,
                                                  const int2* __restrict__ ebuf,
                                                  unsigned* __restrict__ epack2,
                                                  int* __restrict__ rowfine,
                                                  float* __restrict__ dinv,
                                                  int W, int NCH, int E, int K, int N) {
    __shared__ int2 ls[CAP];
    __shared__ unsigned ls2[CAP];
    __shared__ int lh[NKMAX];
    __shared__ int lc[NKMAX];
    __shared__ int ss[512];
    __shared__ float wsum[NB];
    int b = blockIdx.x, t = threadIdx.x;
    size_t i0 = (size_t)b * W;
    int base = gcnt[i0] + bsum[i0 >> 12];
    int next;
    if (b + 1 < K) {
        size_t i1 = (size_t)(b + 1) * W;
        next = gcnt[i1] + bsum[i1 >> 12];
    } else next = E;
    int cnt = next - base;
    int nk = NCH * NB;
    for (int i = t; i < nk; i += 512) lh[i] = 0;
    if (t < NB) wsum[t] = 1.0f;                // self-loop weight
    __syncthreads();
    bool fits = cnt <= CAP;
    for (int i = t; i < cnt; i += 512) {       // hist + stage + weight sums
        int2 e = ebuf[base + i];
        if (fits) ls[i] = e;
        int src = e.x & 0x1FFFF, dl = (e.x >> 17) & (NB - 1);
        atomicAdd(&lh[(src >> CSH) * NB + dl], 1);
        atomicAdd(&wsum[dl], __int_as_float(e.y));
    }
    __syncthreads();
    {   // exclusive scan of lh[0..nk) -> lc
        int v[4]; int s = 0;
#pragma unroll
        for (int q = 0; q < 4; q++) {
            int idx = t * 4 + q;
            v[q] = (idx < nk) ? lh[idx] : 0; s += v[q];
        }
        ss[t] = s;
        __syncthreads();
        for (int d = 1; d < 512; d <<= 1) {
            int x = (t >= d) ? ss[t - d] : 0;
            __syncthreads();
            ss[t] += x;
            __syncthreads();
        }
        int run = (t == 0) ? 0 : ss[t - 1];
#pragma unroll
        for (int q = 0; q < 4; q++) {
            int idx = t * 4 + q;
            if (idx < nk) lc[idx] = run;
            run += v[q];
        }
    }
    __syncthreads();
    for (int i = t; i < nk; i += 512)          // fine CSR (before cursors move)
        rowfine[(size_t)b * nk + i] = base + lc[i];
    __syncthreads();
    if (fits) {
        for (int i = t; i < cnt; i += 512) {   // scatter within LDS
            int2 e = ls[i];
            int src = e.x & 0x1FFFF, dl = (e.x >> 17) & (NB - 1);
            int pos = atomicAdd(&lc[(src >> CSH) * NB + dl], 1);
            ls2[pos] = enc_edge(src, __int_as_float(e.y));
        }
        __syncthreads();
        for (int i = t; i < cnt; i += 512)     // coalesced 4B out
            epack2[base + i] = ls2[i];
    } else {                                   // overflow fallback (rare)
        for (int i = t; i < cnt; i += 512) {
            int2 e = ebuf[base + i];
            int src = e.x & 0x1FFFF, dl = (e.x >> 17) & (NB - 1);
            int pos = atomicAdd(&lc[(src >> CSH) * NB + dl], 1);
            epack2[base + pos] = enc_edge(src, __int_as_float(e.y));
        }
    }
    if (t < NB) {
        int node = b * NB + t;
        if (node < N) dinv[node] = rsqrtf(wsum[t]);
    }
    if (b == 0 && t == 0) rowfine[(size_t)K * nk] = E;   // sentinel
}

// ---- GEMM1 (MFMA bf16): h1b[N,128] = dinv[.] * (x[N,256] @ W1) -------------
#define XS_LD 36
#define WT_LD 260
__global__ __launch_bounds__(256) void k_gemm1(const float* __restrict__ x,
                                               const unsigned short* __restrict__ w1t,
                                               const float* __restrict__ dinv,
                                               unsigned short* __restrict__ h1b, int n) {
    __shared__ __align__(16) unsigned short wt[HID_C * WT_LD];
    __shared__ __align__(16) unsigned short xs[64 * XS_LD];
    int tid  = threadIdx.x;
    int row0 = blockIdx.x * 64;
    for (int it = 0; it < 16; it++) {
        int idx = it * 256 + tid;
        int c = idx >> 5, kc = idx & 31;
        uint4 v = *(const uint4*)(w1t + (size_t)c * IN_C + kc * 8);
        uint2* dst = (uint2*)(wt + c * WT_LD + kc * 8);
        dst[0] = make_uint2(v.x, v.y);
        dst[1] = make_uint2(v.z, v.w);
    }
    int wv = tid >> 6, ln = tid & 63;
    int m = ln & 15, quad = ln >> 4;
    float4v acc[8];
#pragma unroll
    for (int ct = 0; ct < 8; ct++) acc[ct] = (float4v){0.f, 0.f, 0.f, 0.f};

    for (int k0 = 0; k0 < IN_C; k0 += 32) {
        __syncthreads();
        {
            int r = tid >> 2, s4 = tid & 3;
            int gr = row0 + r; if (gr >= n) gr = n - 1;
            const float4* px = (const float4*)(x + (size_t)gr * IN_C + k0 + s4 * 8);
            float4 a = px[0], bq = px[1];
            uint2* d = (uint2*)(xs + r * XS_LD + s4 * 8);
            d[0] = make_uint2(pk2(a.x, a.y), pk2(a.z, a.w));
            d[1] = make_uint2(pk2(bq.x, bq.y), pk2(bq.z, bq.w));
        }
        __syncthreads();
        union { uint2 u[2]; short8 v; } af;
        const uint2* pa = (const uint2*)(xs + (wv * 16 + m) * XS_LD + quad * 8);
        af.u[0] = pa[0]; af.u[1] = pa[1];
#pragma unroll
        for (int ct = 0; ct < 8; ct++) {
            union { uint2 u[2]; short8 v; } bf;
            const uint2* pb = (const uint2*)(wt + (ct * 16 + m) * WT_LD + k0 + quad * 8);
            bf.u[0] = pb[0]; bf.u[1] = pb[1];
            acc[ct] = __builtin_amdgcn_mfma_f32_16x16x32_bf16(af.v, bf.v, acc[ct], 0, 0, 0);
        }
    }
    __syncthreads();
    float4 dv = *(const float4*)(dinv + row0 + wv * 16 + quad * 4);
    const float* dvf = (const float*)&dv;
    unsigned short* ot = wt;
#pragma unroll
    for (int ct = 0; ct < 8; ct++)
#pragma unroll
        for (int r = 0; r < 4; r++)
            ot[(wv * 16 + quad * 4 + r) * 136 + ct * 16 + m] = f2bf(acc[ct][r] * dvf[r]);
    __syncthreads();
#pragma unroll
    for (int p = 0; p < 4; p++) {
        int idx = p * 256 + tid;
        int r = idx >> 4, c8 = idx & 15;
        if (row0 + r < n)
            *(uint4*)(h1b + (size_t)(row0 + r) * HID_C + c8 * 8) =
                *(const uint4*)(ot + r * 136 + c8 * 8);
    }
}

// ---- layer-1 aggregation + fused gemm2: chunk-outer walk, 4-deep MLP -------
// 782 blocks x 8 waves, 2 blocks/CU (launch_bounds 512,4 -> <=128 VGPR, no
// spill). Outermost loop = src chunk (L2 cohort, FETCH-validated R5). Each
// quad walks its dst runs 4 edges at a time: 4 independent dwordx4 gathers
// in flight -> ~256 gathers/CU (R1-level MLP, which sustained 3.7 TB/s).
__global__ __launch_bounds__(512, 4) void k_agg1(const int* __restrict__ rowfine,
                                                 const unsigned* __restrict__ epack2,
                                                 const unsigned short* __restrict__ h1b,
                                                 const float* __restrict__ dinv,
                                                 const float* __restrict__ b1,
                                                 const float* __restrict__ W2,
                                                 float* __restrict__ h2,
                                                 int NCH, int K, int N) {
    int b = blockIdx.x, t = threadIdx.x;
    int wv = t >> 6, lane = t & 63;
    int g = lane >> 4, c16 = lane & 15;
    int nk = NCH * NB;
    const int* rfb = rowfine + (size_t)b * nk;
    const unsigned short* hb = h1b + c16 * 8;  // lane-fixed column offset
    float au[4][8];
#pragma unroll
    for (int u = 0; u < 4; u++)
#pragma unroll
        for (int k = 0; k < 8; k++) au[u][k] = 0.f;

    for (int ch = 0; ch < NCH; ch++) {         // chunk = outermost time axis
        const int* rf = rfb + ch * NB;
#pragma unroll
        for (int u = 0; u < 4; u++) {
            int d = wv * 16 + u * 4 + g;
            int jb = rf[d], je = rf[d + 1];
            for (int j = jb; j < je; j += 4) { // 4 edges in flight per quad
                int j1 = min(j + 1, je - 1);
                int j2 = min(j + 2, je - 1);
                int j3 = min(j + 3, je - 1);
                unsigned r0 = epack2[j],  r1 = epack2[j1];
                unsigned r2 = epack2[j2], r3 = epack2[j3];
                int s0, s1, s2, s3; float w0, w1, w2, w3;
                dec_edge(r0, s0, w0); dec_edge(r1, s1, w1);
                dec_edge(r2, s2, w2); dec_edge(r3, s3, w3);
                w1 = (j + 1 < je) ? w1 : 0.f;
                w2 = (j + 2 < je) ? w2 : 0.f;
                w3 = (j + 3 < je) ? w3 : 0.f;
                uint4 p0 = *(const uint4*)(hb + ((size_t)s0 << 7));
                uint4 p1 = *(const uint4*)(hb + ((size_t)s1 << 7));
                uint4 p2 = *(const uint4*)(hb + ((size_t)s2 << 7));
                uint4 p3 = *(const uint4*)(hb + ((size_t)s3 << 7));
                fma8r(au[u], p0, w0);
                fma8r(au[u], p1, w1);
                fma8r(au[u], p2, w2);
                fma8r(au[u], p3, w3);
            }
        }
    }
    // epilogue: +self, *dinv, +b1, relu, W2 dot, quad butterfly -> h2'
    float4 b1a = *(const float4*)(b1 + c16 * 8);
    float4 b1b = *(const float4*)(b1 + c16 * 8 + 4);
    const float4* wp = (const float4*)(W2 + c16 * 16);
    float4 w0 = wp[0], w1 = wp[1], w2 = wp[2], w3 = wp[3];
#pragma unroll
    for (int u = 0; u < 4; u++) {
        int d = wv * 16 + u * 4 + g;
        int node = b * NB + d;
        bool valid = node < N;
        float di = valid ? dinv[node] : 0.f;
        uint4 sp = make_uint4(0, 0, 0, 0);
        if (valid) sp = *(const uint4*)(h1b + ((size_t)node << 7) + c16 * 8);
        float e0 = fmaxf(fmaf(di, au[u][0] + bl(sp.x), b1a.x), 0.f);
        float e1 = fmaxf(fmaf(di, au[u][1] + bh(sp.x), b1a.y), 0.f);
        float e2 = fmaxf(fmaf(di, au[u][2] + bl(sp.y), b1a.z), 0.f);
        float e3 = fmaxf(fmaf(di, au[u][3] + bh(sp.y), b1a.w), 0.f);
        float e4 = fmaxf(fmaf(di, au[u][4] + bl(sp.z), b1b.x), 0.f);
        float e5 = fmaxf(fmaf(di, au[u][5] + bh(sp.z), b1b.y), 0.f);
        float e6 = fmaxf(fmaf(di, au[u][6] + bl(sp.w), b1b.z), 0.f);
        float e7 = fmaxf(fmaf(di, au[u][7] + bh(sp.w), b1b.w), 0.f);
        float s0 = e0 * w0.x + e1 * w0.z + e2 * w1.x + e3 * w1.z
                 + e4 * w2.x + e5 * w2.z + e6 * w3.x + e7 * w3.z;
        float s1 = e0 * w0.y + e1 * w0.w + e2 * w1.y + e3 * w1.w
                 + e4 * w2.y + e5 * w2.w + e6 * w3.y + e7 * w3.w;
#pragma unroll
        for (int dd = 1; dd < 16; dd <<= 1) {
            s0 += __shfl_xor(s0, dd);
            s1 += __shfl_xor(s1, dd);
        }
        if (c16 == 0 && valid)
            ((float2*)h2)[node] = make_float2(di * s0, di * s1);
    }
}

// ---- layer-2 aggregation: walk over fine CSR, 2 lanes/dst ------------------
__global__ __launch_bounds__(256) void k_agg2(const int* __restrict__ rowfine,
                                              const unsigned* __restrict__ epack2,
                                              const float* __restrict__ h2,
                                              const float* __restrict__ dinv,
                                              const float* __restrict__ b2,
                                              float* __restrict__ out,
                                              int NCH, int K, int N) {
    __shared__ float a2[NB * 2];
    int b = blockIdx.x, t = threadIdx.x;
    int d = t & 127, half = t >> 7;
    int nk = NCH * NB;
    const int* rfb = rowfine + (size_t)b * nk;
    float sx = 0.f, sy = 0.f;
    for (int ch = half; ch < NCH; ch += 2) {
        int jb = rfb[ch * NB + d];
        int je = rfb[ch * NB + d + 1];
        for (int j = jb; j < je; j++) {
            unsigned rec = epack2[j];
            int s; float w;
            dec_edge(rec, s, w);
            float2 v = ((const float2*)h2)[s];
            sx = fmaf(w, v.x, sx);
            sy = fmaf(w, v.y, sy);
        }
    }
    if (half == 1) { a2[d * 2] = sx; a2[d * 2 + 1] = sy; }
    __syncthreads();
    if (half == 0) {
        int node = b * NB + d;
        if (node < N) {
            float di = dinv[node];
            float2 hv = ((const float2*)h2)[node];   // already dinv*H2
            sx += a2[d * 2]; sy += a2[d * 2 + 1];
            ((float2*)out)[node] = make_float2(b2[0] + di * (sx + hv.x),
                                               b2[1] + di * (sy + hv.y));
        }
    }
}

static inline size_t algn16(size_t v) { return (v + 15) & ~(size_t)15; }

extern "C" void kernel_launch(void* const* d_in, const int* in_sizes, int n_in,
                              void* d_out, int out_size, void* d_ws, size_t ws_size,
                              hipStream_t stream) {
    const float* x  = (const float*)d_in[0];
    const int*   ei = (const int*)d_in[1];   // [2,E] int32
    const float* ew = (const float*)d_in[2];
    const float* W1 = (const float*)d_in[3];
    const float* b1 = (const float*)d_in[4];
    const float* W2 = (const float*)d_in[5];
    const float* b2 = (const float*)d_in[6];
    float* out = (float*)d_out;

    int N = in_sizes[0] / IN_C;
    int E = in_sizes[2];
    int K = (N + NB - 1) >> BSH;             // buckets (782)
    int NCH = (N + (1 << CSH) - 1) >> CSH;   // src chunks (13)
    int nk = NCH * NB;                       // fine keys per bucket (1664)
    int W = 256;                             // pass-1 workgroups
    int CHv = (E + W - 1) / W;
    int KW = K * W;                          // coarse hist size (~200k)

    char* ws = (char*)d_ws;
    float* dinv    = (float*)ws; ws += algn16((size_t)N * 4);
    int*   gcnt    = (int*)ws;   ws += algn16((size_t)KW * 4);
    int*   bsum    = (int*)ws;   ws += 8192;
    int*   rowfine = (int*)ws;   ws += algn16(((size_t)K * nk + 1) * 4);
    unsigned* epack2 = (unsigned*)ws; ws += algn16((size_t)E * 4);
    // ebuf (E*8) and h1b (N*256) alias: sortfine consumes ebuf before gemm1
    size_t big = (size_t)E * 8;
    size_t h1sz = (size_t)N * HID_C * 2;
    if (h1sz > big) big = h1sz;
    int2* ebuf = (int2*)ws;
    unsigned short* h1b = (unsigned short*)ws; ws += algn16(big);
    unsigned short* w1t = (unsigned short*)ws; ws += algn16((size_t)HID_C * IN_C * 2);
    float* h2      = (float*)ws; ws += algn16((size_t)N * OUT_C * 4);

    int nb_s4 = (KW + 4095) / 4096;          // 49
    size_t lds_k = (size_t)K * 4;            // ~3.1 KB dynamic LDS

    k_wT      <<<(HID_C * IN_C + 255) / 256, 256, 0, stream>>>(W1, w1t);
    k_count   <<<W, 256, lds_k, stream>>>(ei, gcnt, E, K, W, CHv);
    k_scanA4  <<<nb_s4, 256, 0, stream>>>(gcnt, gcnt, bsum, KW);
    k_scanB   <<<1, 256, 0, stream>>>(bsum, nb_s4);
    k_place   <<<W, 256, lds_k, stream>>>(ei, ew, gcnt, bsum, ebuf, E, K, W, CHv);
    k_sortfine<<<K, 512, 0, stream>>>(gcnt, bsum, ebuf, epack2, rowfine, dinv, W, NCH, E, K, N);
    k_gemm1   <<<(N + 63) / 64, 256, 0, stream>>>(x, w1t, dinv, h1b, N);
    k_agg1    <<<K, 512, 0, stream>>>(rowfine, epack2, h1b, dinv, b1, W2, h2, NCH, K, N);
    k_agg2    <<<K, 256, 0, stream>>>(rowfine, epack2, h2, dinv, b2, out, NCH, K, N);
}